// Round 7
// baseline (274.386 us; speedup 1.0000x reference)
//
#include <hip/hip_runtime.h>
#include <cstdint>
#include <cstddef>

#define EPISODES 128
#define LPAD     512
#define DDIM     512
#define NS_CAP   320
#define GTILE    64
#define NPAIRS   15          // 5*(5+1)/2 tile pairs (NS_CAP/GTILE = 5)
#define CG_ITERS 14
#define GL_F4    4096        // dynamic-LDS float4 capacity (65536 B: spill cols + final reduce)
#define KCH      64          // k per staged chunk in k_gram
#define XBF_ROW  1024        // ushorts per Xbf row: 512 hi + 512 lo
#define GREG     48          // Gram row float4s held in registers per thread

typedef __attribute__((ext_vector_type(8))) __bf16 bf16x8;
typedef __attribute__((ext_vector_type(4))) float  floatx4;

__device__ __forceinline__ int lower_bound_dev(const int* __restrict__ a, int n, int key){
    int lo = 0, hi = n;
    while(lo < hi){
        int m = (lo + hi) >> 1;
        if(a[m] < key) lo = m + 1; else hi = m;
    }
    return lo;
}

__device__ __forceinline__ float4 f4add(float4 a, float4 b){
    return make_float4(a.x+b.x, a.y+b.y, a.z+b.z, a.w+b.w);
}
__device__ __forceinline__ float4 f4fma(float s, float4 a, float4 acc){
    return make_float4(acc.x + s*a.x, acc.y + s*a.y, acc.z + s*a.z, acc.w + s*a.w);
}
__device__ __forceinline__ float f4dot(float4 a, float4 b){
    return a.x*b.x + a.y*b.y + a.z*b.z + a.w*b.w;
}
__device__ __forceinline__ float f4sum(float4 a){ return (a.x+a.y)+(a.z+a.w); }

__device__ __forceinline__ unsigned short f2bf(float x){
    unsigned u = __float_as_uint(x);
    u += 0x7FFFu + ((u >> 16) & 1u);
    return (unsigned short)(u >> 16);
}
__device__ __forceinline__ float bf2f(unsigned short h){
    return __uint_as_float(((unsigned)h) << 16);
}
__device__ __forceinline__ void cvt_hilo(float4 x, ushort4& hh, ushort4& ll){
    hh.x = f2bf(x.x); ll.x = f2bf(x.x - bf2f(hh.x));
    hh.y = f2bf(x.y); ll.y = f2bf(x.y - bf2f(hh.y));
    hh.z = f2bf(x.z); ll.z = f2bf(x.z - bf2f(hh.z));
    hh.w = f2bf(x.w); ll.w = f2bf(x.w - bf2f(hh.w));
}

// wave-uniform-index register broadcast (v_readlane -> SGPR operand)
__device__ __forceinline__ float rdlanef(float v, int l){
    return __int_as_float(__builtin_amdgcn_readlane(__float_as_int(v), l));
}
__device__ __forceinline__ float dotb(float4 g, float4 u, int l){
    return g.x*rdlanef(u.x,l) + g.y*rdlanef(u.y,l)
         + g.z*rdlanef(u.z,l) + g.w*rdlanef(u.w,l);
}
// async 16B/lane global->LDS (linear dest = first-active-lane base + lane*16)
__device__ __forceinline__ void gload_lds16(const void* g, void* l){
    __builtin_amdgcn_global_load_lds(
        (const __attribute__((address_space(1))) void*)g,
        (__attribute__((address_space(3))) void*)l,
        16, 0, 0);
}

// ---------------------------------------------------------------------------
// Kernel 1: fused segmentation + means + per-half row sums + Xbf emission
// (unchanged).
// ---------------------------------------------------------------------------
__global__ __launch_bounds__(256) void k_prep(
        const int* __restrict__ labels, const int* __restrict__ is_query,
        const int* __restrict__ bidx, const float* __restrict__ X, int N,
        int* __restrict__ sup_idx, int* __restrict__ qry_idx,
        int* __restrict__ sup_lab, int* __restrict__ counts,
        float* __restrict__ task_mean, float* __restrict__ pos_mean,
        float* __restrict__ neg_mean, float* __restrict__ row_sums2,
        unsigned short* __restrict__ Xbf)
{
    const int bid  = blockIdx.x;
    const int b    = bid >> 1;
    const int h    = bid & 1;
    const int tid  = threadIdx.x;
    const int lane = tid & 63;
    const int wave = tid >> 6;

    __shared__ int s_start, s_end;
    __shared__ int wq[4];
    __shared__ int s_runq, s_npos;
    __shared__ int   sidx[NS_CAP];
    __shared__ float slabf[NS_CAP];
    __shared__ float4 pa[4][64];
    __shared__ float4 pp[4][64];

    if(tid == 0){
        s_start = lower_bound_dev(bidx, N, b);
        s_end   = lower_bound_dev(bidx, N, b + 1);
        s_runq  = 0;
        s_npos  = 0;
    }
    __syncthreads();
    const int start = s_start, end = s_end;

    for(int base = start; base < end; base += 256){
        int idx   = base + tid;
        bool valid = idx < end;
        int q   = valid ? is_query[idx] : 0;
        int lab = valid ? labels[idx]   : 0;
        unsigned long long m = __ballot(q == 1);
        if(lane == 0) wq[wave] = __popcll(m);
        __syncthreads();
        int woff = 0;
        for(int w = 0; w < wave; w++) woff += wq[w];
        int qbefore = __popcll(m & ((1ull << lane) - 1ull)) + woff;
        int runq0 = s_runq;
        int chunk_total = wq[0] + wq[1] + wq[2] + wq[3];
        if(valid){
            int pos_in_seg = idx - start;
            if(q){
                int qr = runq0 + qbefore;
                if(h == 0 && qr < LPAD) qry_idx[b * LPAD + qr] = idx;
            } else {
                int sr = pos_in_seg - runq0 - qbefore;
                if(sr < LPAD){
                    if(h == 0){
                        sup_idx[b * LPAD + sr] = idx;
                        sup_lab[b * LPAD + sr] = lab;
                    }
                    if(sr < NS_CAP){ sidx[sr] = idx; slabf[sr] = (float)lab; }
                    if(lab == 1) atomicAdd(&s_npos, 1);
                }
            }
        }
        __syncthreads();
        if(tid == 0) s_runq = runq0 + chunk_total;
        __syncthreads();
    }

    const int nq   = s_runq;
    const int ns   = (end - start) - nq;
    const int npos = s_npos;
    const int nneg = ns - npos;
    if(h == 0 && tid == 0){
        counts[b*4 + 0] = ns;
        counts[b*4 + 1] = nq;
        counts[b*4 + 2] = npos;
        counts[b*4 + 3] = nneg;
    }
    const int nsb = min(ns, NS_CAP);

    const float4* X4 = (const float4*)X;
    const int colg = h*64 + lane;            // float4 index in [0,128)
    float4 sa = make_float4(0.f,0.f,0.f,0.f);
    float4 sp = make_float4(0.f,0.f,0.f,0.f);
    int r = wave;
    for(; r + 12 < nsb; r += 16){
        int n0 = sidx[r], n1 = sidx[r+4], n2 = sidx[r+8], n3 = sidx[r+12];
        float l0 = slabf[r], l1 = slabf[r+4], l2 = slabf[r+8], l3 = slabf[r+12];
        float4 x0 = X4[(size_t)n0*128 + colg];
        float4 x1 = X4[(size_t)n1*128 + colg];
        float4 x2 = X4[(size_t)n2*128 + colg];
        float4 x3 = X4[(size_t)n3*128 + colg];
        sa = f4add(sa, f4add(f4add(x0,x1), f4add(x2,x3)));
        sp = f4fma(l0,x0, f4fma(l1,x1, f4fma(l2,x2, f4fma(l3,x3, sp))));
        {
            ushort4 hh, ll;
            size_t rb;
            rb = ((size_t)(b*NS_CAP + r   ) << 10);
            cvt_hilo(x0, hh, ll);
            *(ushort4*)&Xbf[rb + colg*4] = hh;  *(ushort4*)&Xbf[rb + 512 + colg*4] = ll;
            rb = ((size_t)(b*NS_CAP + r+4 ) << 10);
            cvt_hilo(x1, hh, ll);
            *(ushort4*)&Xbf[rb + colg*4] = hh;  *(ushort4*)&Xbf[rb + 512 + colg*4] = ll;
            rb = ((size_t)(b*NS_CAP + r+8 ) << 10);
            cvt_hilo(x2, hh, ll);
            *(ushort4*)&Xbf[rb + colg*4] = hh;  *(ushort4*)&Xbf[rb + 512 + colg*4] = ll;
            rb = ((size_t)(b*NS_CAP + r+12) << 10);
            cvt_hilo(x3, hh, ll);
            *(ushort4*)&Xbf[rb + colg*4] = hh;  *(ushort4*)&Xbf[rb + 512 + colg*4] = ll;
        }
        float r0s = f4sum(x0), r1s = f4sum(x1), r2s = f4sum(x2), r3s = f4sum(x3);
        #pragma unroll
        for(int off = 32; off; off >>= 1){
            r0s += __shfl_xor(r0s, off); r1s += __shfl_xor(r1s, off);
            r2s += __shfl_xor(r2s, off); r3s += __shfl_xor(r3s, off);
        }
        if(lane == 0){
            row_sums2[(b*LPAD + r   )*2 + h] = r0s;
            row_sums2[(b*LPAD + r+4 )*2 + h] = r1s;
            row_sums2[(b*LPAD + r+8 )*2 + h] = r2s;
            row_sums2[(b*LPAD + r+12)*2 + h] = r3s;
        }
    }
    for(; r < nsb; r += 4){
        int n = sidx[r];
        float l = slabf[r];
        float4 x = X4[(size_t)n*128 + colg];
        sa = f4add(sa, x);
        sp = f4fma(l, x, sp);
        {
            ushort4 hh, ll;
            size_t rb = ((size_t)(b*NS_CAP + r) << 10);
            cvt_hilo(x, hh, ll);
            *(ushort4*)&Xbf[rb + colg*4] = hh;  *(ushort4*)&Xbf[rb + 512 + colg*4] = ll;
        }
        float rs = f4sum(x);
        #pragma unroll
        for(int off = 32; off; off >>= 1) rs += __shfl_xor(rs, off);
        if(lane == 0) row_sums2[(b*LPAD + r)*2 + h] = rs;
    }
    // zero-pad Xbf rows [nsb, ceil64(nsb)) so k_gram's staged tails are finite
    {
        const int padf = min((nsb + 63) & ~63, NS_CAP);
        ushort4 z; z.x = z.y = z.z = z.w = 0;
        for(int rz = nsb + wave; rz < padf; rz += 4){
            size_t rb = ((size_t)(b*NS_CAP + rz) << 10);
            *(ushort4*)&Xbf[rb + colg*4] = z;
            *(ushort4*)&Xbf[rb + 512 + colg*4] = z;
        }
    }
    pa[wave][lane] = sa;
    pp[wave][lane] = sp;
    __syncthreads();
    if(tid < 64){
        float4 A = f4add(f4add(pa[0][tid],pa[1][tid]), f4add(pa[2][tid],pa[3][tid]));
        float4 P = f4add(f4add(pp[0][tid],pp[1][tid]), f4add(pp[2][tid],pp[3][tid]));
        float4 Nn = make_float4(A.x-P.x, A.y-P.y, A.z-P.z, A.w-P.w);
        float ia = 1.f/(float)ns, ip = 1.f/(float)npos, in = 1.f/(float)nneg;
        int c = b*128 + h*64 + tid;
        ((float4*)task_mean)[c] = make_float4(A.x*ia, A.y*ia, A.z*ia, A.w*ia);
        ((float4*)pos_mean )[c] = make_float4(P.x*ip, P.y*ip, P.z*ip, P.w*ip);
        ((float4*)neg_mean )[c] = make_float4(Nn.x*in, Nn.y*in, Nn.z*in, Nn.w*in);
    }
}

// ---------------------------------------------------------------------------
// Kernel 2: Gram via bf16 MFMA, staging from precomputed Xbf with
// global_load_lds + XOR swizzle (unchanged).
// ---------------------------------------------------------------------------
__global__ __launch_bounds__(256) void k_gram(
        const unsigned short* __restrict__ Xbf,
        const int* __restrict__ counts, float* __restrict__ G0)
{
    const int bid = blockIdx.x;
    const int b   = bid / NPAIRS;
    int tp = bid % NPAIRS;
    int ti = 0;
    while((ti+1)*(ti+2)/2 <= tp) ti++;
    const int tj  = tp - ti*(ti+1)/2;          // ti >= tj
    const int tid = threadIdx.x;
    const int lane = tid & 63;
    const int wave = tid >> 6;

    const int ns  = counts[b*4 + 0];
    const int nsc = min(ns, NS_CAP);
    if(ti * GTILE >= nsc) return;
    const bool diag = (ti == tj);

    // planes (ushort idx): Ahi 0, Alo 4096, Bhi 8192, Blo 12288 (32768 B total)
    __shared__ __align__(16) unsigned short SM[4 * GTILE * 64];
    unsigned short* const SAh = SM;
    unsigned short* const SAl = SM + 4096;
    const unsigned short* Bh = diag ? SAh : (SM + 8192);
    const unsigned short* Bl = diag ? SAl : (SM + 12288);

    const int r8  = lane >> 3;                 // row within 8-row group (0..7)
    const int blk = lane & 7;                  // 16B block within row
    const int fr = lane & 15;
    const int fq = (lane >> 4) * 8;
    const int ry = (wave >> 1) * 32;
    const int cx = (wave & 1) * 32;

    floatx4 acc[2][2];
    acc[0][0] = (floatx4){0.f,0.f,0.f,0.f};
    acc[0][1] = (floatx4){0.f,0.f,0.f,0.f};
    acc[1][0] = (floatx4){0.f,0.f,0.f,0.f};
    acc[1][1] = (floatx4){0.f,0.f,0.f,0.f};

    const int xr = blk ^ r8;                   // source-side swizzle
    for(int k0 = 0; k0 < DDIM; k0 += KCH){
        __syncthreads();
        #pragma unroll
        for(int i = 0; i < 4; i++){
            int e  = wave*4 + i;
            int pl = e >> 3, g = e & 7;
            int row = g*8 + r8;
            const unsigned short* src = Xbf
                + ((size_t)(b*NS_CAP + ti*GTILE + row) << 10)
                + pl*512 + k0 + (xr << 3);
            gload_lds16(src, SM + pl*4096 + row*64 + blk*8);
        }
        if(!diag){
            #pragma unroll
            for(int i = 0; i < 4; i++){
                int e  = wave*4 + i;
                int pl = e >> 3, g = e & 7;
                int row = g*8 + r8;
                const unsigned short* src = Xbf
                    + ((size_t)(b*NS_CAP + tj*GTILE + row) << 10)
                    + pl*512 + k0 + (xr << 3);
                gload_lds16(src, SM + 8192 + pl*4096 + row*64 + blk*8);
            }
        }
        __syncthreads();
        #pragma unroll
        for(int ks = 0; ks < KCH; ks += 32){
            const int j  = (ks + fq) >> 3;
            const int jx = (j ^ (fr & 7)) << 3; // swizzled ushort offset in row
            bf16x8 ah0 = *(const bf16x8*)&SAh[(ry      + fr)*64 + jx];
            bf16x8 ah1 = *(const bf16x8*)&SAh[(ry + 16 + fr)*64 + jx];
            bf16x8 al0 = *(const bf16x8*)&SAl[(ry      + fr)*64 + jx];
            bf16x8 al1 = *(const bf16x8*)&SAl[(ry + 16 + fr)*64 + jx];
            bf16x8 bh0 = *(const bf16x8*)&Bh [(cx      + fr)*64 + jx];
            bf16x8 bh1 = *(const bf16x8*)&Bh [(cx + 16 + fr)*64 + jx];
            bf16x8 bl0 = *(const bf16x8*)&Bl [(cx      + fr)*64 + jx];
            bf16x8 bl1 = *(const bf16x8*)&Bl [(cx + 16 + fr)*64 + jx];
            acc[0][0] = __builtin_amdgcn_mfma_f32_16x16x32_bf16(ah0, bh0, acc[0][0], 0,0,0);
            acc[0][1] = __builtin_amdgcn_mfma_f32_16x16x32_bf16(ah0, bh1, acc[0][1], 0,0,0);
            acc[1][0] = __builtin_amdgcn_mfma_f32_16x16x32_bf16(ah1, bh0, acc[1][0], 0,0,0);
            acc[1][1] = __builtin_amdgcn_mfma_f32_16x16x32_bf16(ah1, bh1, acc[1][1], 0,0,0);
            acc[0][0] = __builtin_amdgcn_mfma_f32_16x16x32_bf16(ah0, bl0, acc[0][0], 0,0,0);
            acc[0][1] = __builtin_amdgcn_mfma_f32_16x16x32_bf16(ah0, bl1, acc[0][1], 0,0,0);
            acc[1][0] = __builtin_amdgcn_mfma_f32_16x16x32_bf16(ah1, bl0, acc[1][0], 0,0,0);
            acc[1][1] = __builtin_amdgcn_mfma_f32_16x16x32_bf16(ah1, bl1, acc[1][1], 0,0,0);
            acc[0][0] = __builtin_amdgcn_mfma_f32_16x16x32_bf16(al0, bh0, acc[0][0], 0,0,0);
            acc[0][1] = __builtin_amdgcn_mfma_f32_16x16x32_bf16(al0, bh1, acc[0][1], 0,0,0);
            acc[1][0] = __builtin_amdgcn_mfma_f32_16x16x32_bf16(al1, bh0, acc[1][0], 0,0,0);
            acc[1][1] = __builtin_amdgcn_mfma_f32_16x16x32_bf16(al1, bh1, acc[1][1], 0,0,0);
        }
    }

    float4* Gf4 = (float4*)(G0 + (size_t)b * NS_CAP * NS_CAP);
    const int q = lane >> 4, j = lane & 15;
    #pragma unroll
    for(int sy = 0; sy < 2; sy++)
        #pragma unroll
        for(int sx = 0; sx < 2; sx++){
            int cq = ((ti*GTILE + ry + sy*16) >> 2) + q;
            int t  = tj*GTILE + cx + sx*16 + j;
            Gf4[(size_t)cq * NS_CAP + t] =
                make_float4(acc[sy][sx].x, acc[sy][sx].y, acc[sy][sx].z, acc[sy][sx].w);
        }

    if(!diag){
        __syncthreads();
        float* Tb = (float*)SM;                // 64 x 68 floats = 17408 B <= 32768
        #pragma unroll
        for(int sy = 0; sy < 2; sy++)
            #pragma unroll
            for(int sx = 0; sx < 2; sx++){
                int r0 = ry + sy*16 + 4*q;
                int c  = cx + sx*16 + j;
                Tb[(r0+0)*68 + c] = acc[sy][sx].x;
                Tb[(r0+1)*68 + c] = acc[sy][sx].y;
                Tb[(r0+2)*68 + c] = acc[sy][sx].z;
                Tb[(r0+3)*68 + c] = acc[sy][sx].w;
            }
        __syncthreads();
        for(int e = tid; e < 16*GTILE; e += 256){
            int cc = e >> 6;
            int r  = e & 63;
            float4 v = *(const float4*)&Tb[r*68 + 4*cc];
            Gf4[(size_t)(tj*16 + cc) * NS_CAP + ti*GTILE + r] = v;
        }
    }
}

// ---------------------------------------------------------------------------
// Kernel 3: coefficient-space CG + fused query output.
// v9: __launch_bounds__(512, 2) pins min 2 waves/EU -> VGPR budget 256, so
// the register-resident Gram row g[48] (192 VGPR) stays in registers. v8's
// allocator targeted 4 waves/EU (VGPR_Count=128) and spilled g[] to scratch
// (L3-served; invisible in FETCH/WRITE) -> 103 us. Grid = 256 blocks = 256
// CUs, so 1 block/CU costs nothing. No other changes.
// ---------------------------------------------------------------------------
extern __shared__ float4 gl4[];                // GL_F4 float4 (65536 B)

__global__ __launch_bounds__(512, 2) void k_cgc(
        const float* __restrict__ X, const float* __restrict__ G0,
        const int* __restrict__ sup_idx, const int* __restrict__ sup_lab,
        const int* __restrict__ counts, const float* __restrict__ row_sums2,
        const int* __restrict__ qry_idx,
        const float* __restrict__ pos_mean, const float* __restrict__ neg_mean,
        const float* __restrict__ log_scale, float* __restrict__ out)
{
    const int bid  = blockIdx.x;
    const int sys  = ((bid & 7) << 5) | (bid >> 3);   // pair-local XCD swizzle
    const int b    = sys >> 1;
    const int cls  = sys & 1;
    const int tid  = threadIdx.x;
    const int lane = tid & 63;
    const int wave = tid >> 6;

    __shared__ __align__(16) float u[NS_CAP];
    __shared__ int   idx_l[NS_CAP];
    __shared__ int   qidx_l[LPAD];
    __shared__ float P[64];                    // [wave*8 + k], k<5 valid
    __shared__ __align__(16) float4 vv[128];   // solved v (D=512)

    const int ns   = counts[b*4 + 0];
    const int nsc  = min(ns, NS_CAP);
    const int nq   = counts[b*4 + 1];
    const int nqc  = min(nq, LPAD);
    const int ncls = cls ? counts[b*4 + 2] : counts[b*4 + 3];
    const float c_task = 0.9f / (float)(ns - 1);
    const float c_cls  = 0.1f / (float)(ncls - 1);
    const float inv_ns = 1.f / (float)ns;
    const float inv_nc = 1.f / (float)ncls;
    const float4* G4 = (const float4*)(G0 + (size_t)b * NS_CAP * NS_CAP);
    const float4* u4 = (const float4*)u;
    const int nf4 = (nsc + 3) >> 2;

    const bool mth = tid < NS_CAP;
    const bool own = tid < nsc;
    float mfl = 0.f, sraw = 0.f;
    if(own){
        mfl  = (sup_lab[b*LPAD + tid] == cls) ? 1.f : 0.f;
        float2 rs = ((const float2*)row_sums2)[b*LPAD + tid];
        sraw = rs.x + rs.y;
    }
    for(int s = tid; s < nsc; s += 512) idx_l[s] = sup_idx[b*LPAD + s];
    qidx_l[tid] = qry_idx[b*LPAD + tid];       // 512 threads cover LPAD exactly
    if(tid < 64) P[tid] = 0.f;                 // zero pad slots (k>=5)

    const bool fastu   = (nf4 <= 64);          // nsc <= 256 (always, in practice)
    const bool haverow = ((wave << 6) < nsc);  // wave-uniform: wave owns >=1 row

    // Register-resident Gram row: g[c4] = G4[c4*NS_CAP + tid], zero-masked for
    // columns >= nsc. Fully unrolled, compile-time indices -> promoted to VGPRs.
    float4 g[GREG];
    if(fastu && haverow){
        #pragma unroll
        for(int c4 = 0; c4 < GREG; c4++){
            float4 v = G4[(size_t)c4 * NS_CAP + tid];
            bool live = (4*c4 < nsc);
            g[c4].x = live ? v.x : 0.f;
            g[c4].y = live ? v.y : 0.f;
            g[c4].z = live ? v.z : 0.f;
            g[c4].w = live ? v.w : 0.f;
        }
    }

    // Spill columns (GREG <= c4 < nf4, only when nsc > 4*GREG=192): stage once.
    if(fastu && nf4 > GREG){
        const int nchunk = (nsc + 63) >> 6;
        for(int ch = 0; ch < nchunk; ch++){
            const int t = (ch << 6) + lane;
            const bool act = t < nsc;
            for(int c4 = GREG + wave; c4 < nf4; c4 += 8){
                if(act) gload_lds16(G4 + (size_t)c4 * NS_CAP + t,
                                    gl4 + (c4 - GREG) * nsc + t);
            }
        }
    }
    __syncthreads();   // orders P-zero before bundle's P writes; drains staging

    auto bundle = [&](float v0, float v1, float v2, float v3, float v4,
                      float* S){
        #pragma unroll
        for(int off = 32; off; off >>= 1){
            v0 += __shfl_xor(v0, off); v1 += __shfl_xor(v1, off);
            v2 += __shfl_xor(v2, off); v3 += __shfl_xor(v3, off);
            v4 += __shfl_xor(v4, off);
        }
        if(lane == 0){
            P[wave*8 + 0] = v0; P[wave*8 + 1] = v1; P[wave*8 + 2] = v2;
            P[wave*8 + 3] = v3; P[wave*8 + 4] = v4;
        }
        __syncthreads();                       // (a)
        float pv = P[lane];
        pv += __shfl_xor(pv, 8);
        pv += __shfl_xor(pv, 16);
        pv += __shfl_xor(pv, 32);              // pv = S[lane & 7]
        S[0] = __shfl(pv, 0); S[1] = __shfl(pv, 1); S[2] = __shfl(pv, 2);
        S[3] = __shfl(pv, 3); S[4] = __shfl(pv, 4);
    };

    auto matvec = [&]() -> float {
        float t = 0.f;
        if(fastu){
            if(haverow){
                // one ds_read_b128 per wave: lane l caches u4[l]; all 64 lanes
                // execute (wave-uniform guard), pinned against sinking.
                float4 ubc = u4[lane < nf4 ? lane : 0];
                asm volatile("" : "+v"(ubc.x), "+v"(ubc.y), "+v"(ubc.z), "+v"(ubc.w));
                float s0 = 0.f, s1 = 0.f, s2 = 0.f, s3 = 0.f;
                #pragma unroll
                for(int c4 = 0; c4 < GREG; c4 += 4){
                    s0 += dotb(g[c4+0], ubc, c4+0);
                    s1 += dotb(g[c4+1], ubc, c4+1);
                    s2 += dotb(g[c4+2], ubc, c4+2);
                    s3 += dotb(g[c4+3], ubc, c4+3);
                }
                // spill columns from LDS (rare; u broadcast via LDS read)
                if(nf4 > GREG){
                    const int row = own ? tid : (nsc - 1);
                    for(int c4 = GREG; c4 < nf4; c4++)
                        s0 += f4dot(gl4[(c4 - GREG)*nsc + row], u4[c4]);
                }
                t = (s0 + s1) + (s2 + s3);
            }
            return own ? t : 0.f;
        } else {
            // fallback (nsc > 256; does not occur for this input): global reads
            float s0 = 0.f, s1 = 0.f, s2 = 0.f, s3 = 0.f;
            if(own){
                int c4 = 0;
                for(; c4 + 4 <= nf4; c4 += 4){
                    float4 h0 = G4[(size_t)(c4+0)*NS_CAP + tid];
                    float4 h1 = G4[(size_t)(c4+1)*NS_CAP + tid];
                    float4 h2 = G4[(size_t)(c4+2)*NS_CAP + tid];
                    float4 h3 = G4[(size_t)(c4+3)*NS_CAP + tid];
                    s0 += f4dot(h0, u4[c4+0]); s1 += f4dot(h1, u4[c4+1]);
                    s2 += f4dot(h2, u4[c4+2]); s3 += f4dot(h3, u4[c4+3]);
                }
                for(; c4 < nf4; c4++) s0 += f4dot(G4[(size_t)c4*NS_CAP + tid], u4[c4]);
            }
            float tt = (s0 + s1) + (s2 + s3);
            return own ? tt : 0.f;
        }
    };

    // init: r0 = -10 * A * 1  (t-image of p=1_D is the row-sum vector)
    float S[5];
    bundle(sraw, mfl * sraw, 0.f, 0.f, 0.f, S);
    float A0 = S[0] * inv_ns, A1 = S[1] * inv_nc;
    float cr = own ? -10.f * (c_task*(sraw - A0) + mfl*c_cls*(sraw - A1)) : 0.f;
    if(mth) u[tid] = cr;                       // cr = 0 for !own
    __syncthreads();                           // (b)
    float tr = matvec();

    float cp = 0.f, cq = 0.f, tq = 0.f, cx = 0.f;
    float gamma_old = 1.f, alpha_old = 1.f;
    bool first = true;

    for(int it = 0; it < CG_ITERS; ++it){
        // bundle: S1=Σtr, S2=Σm·tr, S3=Σtr², S4=Σm·tr², S5=Σtr·cr
        bundle(tr, mfl*tr, tr*tr, mfl*tr*tr, tr*cr, S);
        A0 = S[0] * inv_ns; A1 = S[1] * inv_nc;
        float gamma = S[4];                                  // (r,r)
        float delta = 0.1f*gamma + c_task*(S[2] - S[0]*A0)
                                 + c_cls *(S[3] - S[1]*A1);  // (r,Mr)
        float beta  = first ? 0.f : gamma / gamma_old;
        float denom = first ? delta : (delta - beta * gamma / alpha_old);
        float alpha = (gamma < 1e-30f) ? 0.f : gamma / denom;
        float ur = own ? (c_task*(tr - A0) + mfl*c_cls*(tr - A1)) : 0.f;
        float cw = 0.1f*cr + ur;                             // c of w = M r
        cp = cr + beta * cp;
        cq = cw + beta * cq;
        cx += alpha * cp;
        if(it == CG_ITERS - 1 || gamma < 1e-26f) break;      // final sweep skipped
        if(mth) u[tid] = ur;
        __syncthreads();                                     // (b)
        float gv = matvec();                                 // G0 * u_r
        float tw = 0.1f*tr + gv;                             // t of w
        tq = tw + beta * tq;
        cr -= alpha * cq;
        tr -= alpha * tq;
        gamma_old = gamma; alpha_old = alpha; first = false;
    }

    // v = 10*1 + Xs^T c_x  (accumulated into vv[] in LDS)
    __syncthreads();
    if(mth) u[tid] = own ? cx : 0.f;
    __syncthreads();
    const float4* X4 = (const float4*)X;
    const int f4c = tid & 127;
    const int rg  = tid >> 7;
    float4 acc = make_float4(0.f,0.f,0.f,0.f);
    int s = rg;
    for(; s + 28 < nsc; s += 32){
        int n0 = idx_l[s],    n1 = idx_l[s+4],  n2 = idx_l[s+8],  n3 = idx_l[s+12];
        int n4 = idx_l[s+16], n5 = idx_l[s+20], n6 = idx_l[s+24], n7 = idx_l[s+28];
        float w0 = u[s],    w1 = u[s+4],  w2 = u[s+8],  w3 = u[s+12];
        float w4 = u[s+16], w5 = u[s+20], w6 = u[s+24], w7 = u[s+28];
        float4 x0 = X4[(size_t)n0*128 + f4c];
        float4 x1 = X4[(size_t)n1*128 + f4c];
        float4 x2 = X4[(size_t)n2*128 + f4c];
        float4 x3 = X4[(size_t)n3*128 + f4c];
        float4 x4 = X4[(size_t)n4*128 + f4c];
        float4 x5 = X4[(size_t)n5*128 + f4c];
        float4 x6 = X4[(size_t)n6*128 + f4c];
        float4 x7 = X4[(size_t)n7*128 + f4c];
        acc = f4fma(w0,x0, f4fma(w1,x1, f4fma(w2,x2, f4fma(w3,x3, acc))));
        acc = f4fma(w4,x4, f4fma(w5,x5, f4fma(w6,x6, f4fma(w7,x7, acc))));
    }
    for(; s < nsc; s += 4)
        acc = f4fma(u[s], X4[(size_t)idx_l[s]*128 + f4c], acc);
    gl4[rg*128 + f4c] = acc;
    __syncthreads();
    if(tid < 128){
        float4 v = f4add(f4add(gl4[tid], gl4[128+tid]),
                         f4add(gl4[256+tid], gl4[384+tid]));
        v.x += 10.f; v.y += 10.f; v.z += 10.f; v.w += 10.f;
        vv[tid] = v;
    }

    // sm = sum(mean_c), mv = mean_c . v  (one bundle; vv made visible by its
    // internal barrier — each tid<128 reads only its own vv element here)
    const float* mean_c = cls ? pos_mean : neg_mean;
    float psm = 0.f, pmv = 0.f;
    if(tid < 128){
        float4 m4 = ((const float4*)mean_c)[b*128 + tid];
        float4 v  = vv[tid];
        psm = f4sum(m4);
        pmv = f4dot(m4, v);
    }
    bundle(psm, pmv, 0.f, 0.f, 0.f, S);
    const float sm = S[0], mv = S[1];
    const float scale = expf(log_scale[0]);

    // query loop: 8 waves, 2 rows per wave per iteration
    const float4 va = vv[lane], vb = vv[lane + 64];
    for(int r = wave; r < nqc; r += 16){
        int r2 = r + 8;
        bool has2 = r2 < nqc;
        int n  = qidx_l[r];
        int n2 = qidx_l[has2 ? r2 : r];
        const float4* xr = (const float4*)(X + (size_t)n  * DDIM);
        const float4* yr = (const float4*)(X + (size_t)n2 * DDIM);
        float4 x0 = xr[lane], x1 = xr[lane + 64];
        float4 y0 = yr[lane], y1 = yr[lane + 64];
        float t1 = f4dot(x0, va) + f4dot(x1, vb);
        float s1 = f4sum(x0) + f4sum(x1);
        float t2 = f4dot(y0, va) + f4dot(y1, vb);
        float s2 = f4sum(y0) + f4sum(y1);
        #pragma unroll
        for(int off = 32; off; off >>= 1){
            t1 += __shfl_xor(t1, off);
            s1 += __shfl_xor(s1, off);
            t2 += __shfl_xor(t2, off);
            s2 += __shfl_xor(s2, off);
        }
        if(lane == 0){
            out[(size_t)(b*LPAD + r)*2 + cls] = (t1 - mv) * (s1 - sm) * scale;
            if(has2)
                out[(size_t)(b*LPAD + r2)*2 + cls] = (t2 - mv) * (s2 - sm) * scale;
        }
    }
    for(int r = nqc + tid; r < LPAD; r += 512)
        out[(size_t)(b*LPAD + r)*2 + cls] = 0.f;
}

// ---------------------------------------------------------------------------
extern "C" void kernel_launch(void* const* d_in, const int* in_sizes, int n_in,
                              void* d_out, int out_size, void* d_ws, size_t ws_size,
                              hipStream_t stream)
{
    const float* X         = (const float*)d_in[0];
    const float* log_scale = (const float*)d_in[1];
    const int*   labels    = (const int*)d_in[2];
    const int*   is_query  = (const int*)d_in[3];
    const int*   bidx      = (const int*)d_in[4];
    const int N = in_sizes[2];

    char* ws = (char*)d_ws;
    auto alloc = [&](size_t bytes) -> char* {
        char* p = ws;
        ws += (bytes + 255) & ~(size_t)255;
        return p;
    };
    int*   sup_idx   = (int*)  alloc((size_t)EPISODES * LPAD * sizeof(int));
    int*   qry_idx   = (int*)  alloc((size_t)EPISODES * LPAD * sizeof(int));
    int*   sup_lab   = (int*)  alloc((size_t)EPISODES * LPAD * sizeof(int));
    int*   counts    = (int*)  alloc((size_t)EPISODES * 4 * sizeof(int));
    float* task_mean = (float*)alloc((size_t)EPISODES * DDIM * sizeof(float));
    float* pos_mean  = (float*)alloc((size_t)EPISODES * DDIM * sizeof(float));
    float* neg_mean  = (float*)alloc((size_t)EPISODES * DDIM * sizeof(float));
    float* row_sums2 = (float*)alloc((size_t)EPISODES * LPAD * 2 * sizeof(float));
    float* G0        = (float*)alloc((size_t)EPISODES * NS_CAP * NS_CAP * sizeof(float));
    unsigned short* Xbf = (unsigned short*)alloc(
                          (size_t)EPISODES * NS_CAP * XBF_ROW * sizeof(unsigned short));
    (void)ws_size;
    (void)task_mean;

    k_prep<<<EPISODES*2, 256, 0, stream>>>(labels, is_query, bidx, X, N,
                                           sup_idx, qry_idx, sup_lab, counts,
                                           task_mean, pos_mean, neg_mean, row_sums2,
                                           Xbf);
    k_gram<<<EPISODES * NPAIRS, 256, 0, stream>>>(Xbf, counts, G0);
    k_cgc<<<EPISODES * 2, 512, GL_F4 * sizeof(float4), stream>>>(
                                            X, G0, sup_idx, sup_lab, counts,
                                            row_sums2, qry_idx, pos_mean, neg_mean,
                                            log_scale, (float*)d_out);
}

// Round 8
// 274.025 us; speedup vs baseline: 1.0013x; 1.0013x over previous
//
#include <hip/hip_runtime.h>
#include <cstdint>
#include <cstddef>

#define EPISODES 128
#define LPAD     512
#define DDIM     512
#define NS_CAP   320
#define GTILE    64
#define NPAIRS   15          // 5*(5+1)/2 tile pairs (NS_CAP/GTILE = 5)
#define CG_ITERS 14
#define GL_F4    4096        // dynamic-LDS float4 capacity (65536 B: spill cols + final reduce)
#define KCH      64          // k per staged chunk in k_gram
#define XBF_ROW  1024        // ushorts per Xbf row: 512 hi + 512 lo
#define GREG     48          // Gram row float4s held in registers per thread

typedef __attribute__((ext_vector_type(8))) __bf16 bf16x8;
typedef __attribute__((ext_vector_type(4))) float  floatx4;

__device__ __forceinline__ int lower_bound_dev(const int* __restrict__ a, int n, int key){
    int lo = 0, hi = n;
    while(lo < hi){
        int m = (lo + hi) >> 1;
        if(a[m] < key) lo = m + 1; else hi = m;
    }
    return lo;
}

__device__ __forceinline__ float4 f4add(float4 a, float4 b){
    return make_float4(a.x+b.x, a.y+b.y, a.z+b.z, a.w+b.w);
}
__device__ __forceinline__ float4 f4fma(float s, float4 a, float4 acc){
    return make_float4(acc.x + s*a.x, acc.y + s*a.y, acc.z + s*a.z, acc.w + s*a.w);
}
__device__ __forceinline__ float f4dot(float4 a, float4 b){
    return a.x*b.x + a.y*b.y + a.z*b.z + a.w*b.w;
}
__device__ __forceinline__ float f4sum(float4 a){ return (a.x+a.y)+(a.z+a.w); }

__device__ __forceinline__ unsigned short f2bf(float x){
    unsigned u = __float_as_uint(x);
    u += 0x7FFFu + ((u >> 16) & 1u);
    return (unsigned short)(u >> 16);
}
__device__ __forceinline__ float bf2f(unsigned short h){
    return __uint_as_float(((unsigned)h) << 16);
}
__device__ __forceinline__ void cvt_hilo(float4 x, ushort4& hh, ushort4& ll){
    hh.x = f2bf(x.x); ll.x = f2bf(x.x - bf2f(hh.x));
    hh.y = f2bf(x.y); ll.y = f2bf(x.y - bf2f(hh.y));
    hh.z = f2bf(x.z); ll.z = f2bf(x.z - bf2f(hh.z));
    hh.w = f2bf(x.w); ll.w = f2bf(x.w - bf2f(hh.w));
}

// wave-uniform-index register broadcast (v_readlane -> SGPR operand)
__device__ __forceinline__ float rdlanef(float v, int l){
    return __int_as_float(__builtin_amdgcn_readlane(__float_as_int(v), l));
}
__device__ __forceinline__ float dotb(float4 g, float4 u, int l){
    return g.x*rdlanef(u.x,l) + g.y*rdlanef(u.y,l)
         + g.z*rdlanef(u.z,l) + g.w*rdlanef(u.w,l);
}
// async 16B/lane global->LDS (linear dest = first-active-lane base + lane*16)
__device__ __forceinline__ void gload_lds16(const void* g, void* l){
    __builtin_amdgcn_global_load_lds(
        (const __attribute__((address_space(1))) void*)g,
        (__attribute__((address_space(3))) void*)l,
        16, 0, 0);
}

// ---------------------------------------------------------------------------
// Kernel 1: fused segmentation + means + per-half row sums + Xbf emission
// (unchanged).
// ---------------------------------------------------------------------------
__global__ __launch_bounds__(256) void k_prep(
        const int* __restrict__ labels, const int* __restrict__ is_query,
        const int* __restrict__ bidx, const float* __restrict__ X, int N,
        int* __restrict__ sup_idx, int* __restrict__ qry_idx,
        int* __restrict__ sup_lab, int* __restrict__ counts,
        float* __restrict__ task_mean, float* __restrict__ pos_mean,
        float* __restrict__ neg_mean, float* __restrict__ row_sums2,
        unsigned short* __restrict__ Xbf)
{
    const int bid  = blockIdx.x;
    const int b    = bid >> 1;
    const int h    = bid & 1;
    const int tid  = threadIdx.x;
    const int lane = tid & 63;
    const int wave = tid >> 6;

    __shared__ int s_start, s_end;
    __shared__ int wq[4];
    __shared__ int s_runq, s_npos;
    __shared__ int   sidx[NS_CAP];
    __shared__ float slabf[NS_CAP];
    __shared__ float4 pa[4][64];
    __shared__ float4 pp[4][64];

    if(tid == 0){
        s_start = lower_bound_dev(bidx, N, b);
        s_end   = lower_bound_dev(bidx, N, b + 1);
        s_runq  = 0;
        s_npos  = 0;
    }
    __syncthreads();
    const int start = s_start, end = s_end;

    for(int base = start; base < end; base += 256){
        int idx   = base + tid;
        bool valid = idx < end;
        int q   = valid ? is_query[idx] : 0;
        int lab = valid ? labels[idx]   : 0;
        unsigned long long m = __ballot(q == 1);
        if(lane == 0) wq[wave] = __popcll(m);
        __syncthreads();
        int woff = 0;
        for(int w = 0; w < wave; w++) woff += wq[w];
        int qbefore = __popcll(m & ((1ull << lane) - 1ull)) + woff;
        int runq0 = s_runq;
        int chunk_total = wq[0] + wq[1] + wq[2] + wq[3];
        if(valid){
            int pos_in_seg = idx - start;
            if(q){
                int qr = runq0 + qbefore;
                if(h == 0 && qr < LPAD) qry_idx[b * LPAD + qr] = idx;
            } else {
                int sr = pos_in_seg - runq0 - qbefore;
                if(sr < LPAD){
                    if(h == 0){
                        sup_idx[b * LPAD + sr] = idx;
                        sup_lab[b * LPAD + sr] = lab;
                    }
                    if(sr < NS_CAP){ sidx[sr] = idx; slabf[sr] = (float)lab; }
                    if(lab == 1) atomicAdd(&s_npos, 1);
                }
            }
        }
        __syncthreads();
        if(tid == 0) s_runq = runq0 + chunk_total;
        __syncthreads();
    }

    const int nq   = s_runq;
    const int ns   = (end - start) - nq;
    const int npos = s_npos;
    const int nneg = ns - npos;
    if(h == 0 && tid == 0){
        counts[b*4 + 0] = ns;
        counts[b*4 + 1] = nq;
        counts[b*4 + 2] = npos;
        counts[b*4 + 3] = nneg;
    }
    const int nsb = min(ns, NS_CAP);

    const float4* X4 = (const float4*)X;
    const int colg = h*64 + lane;            // float4 index in [0,128)
    float4 sa = make_float4(0.f,0.f,0.f,0.f);
    float4 sp = make_float4(0.f,0.f,0.f,0.f);
    int r = wave;
    for(; r + 12 < nsb; r += 16){
        int n0 = sidx[r], n1 = sidx[r+4], n2 = sidx[r+8], n3 = sidx[r+12];
        float l0 = slabf[r], l1 = slabf[r+4], l2 = slabf[r+8], l3 = slabf[r+12];
        float4 x0 = X4[(size_t)n0*128 + colg];
        float4 x1 = X4[(size_t)n1*128 + colg];
        float4 x2 = X4[(size_t)n2*128 + colg];
        float4 x3 = X4[(size_t)n3*128 + colg];
        sa = f4add(sa, f4add(f4add(x0,x1), f4add(x2,x3)));
        sp = f4fma(l0,x0, f4fma(l1,x1, f4fma(l2,x2, f4fma(l3,x3, sp))));
        {
            ushort4 hh, ll;
            size_t rb;
            rb = ((size_t)(b*NS_CAP + r   ) << 10);
            cvt_hilo(x0, hh, ll);
            *(ushort4*)&Xbf[rb + colg*4] = hh;  *(ushort4*)&Xbf[rb + 512 + colg*4] = ll;
            rb = ((size_t)(b*NS_CAP + r+4 ) << 10);
            cvt_hilo(x1, hh, ll);
            *(ushort4*)&Xbf[rb + colg*4] = hh;  *(ushort4*)&Xbf[rb + 512 + colg*4] = ll;
            rb = ((size_t)(b*NS_CAP + r+8 ) << 10);
            cvt_hilo(x2, hh, ll);
            *(ushort4*)&Xbf[rb + colg*4] = hh;  *(ushort4*)&Xbf[rb + 512 + colg*4] = ll;
            rb = ((size_t)(b*NS_CAP + r+12) << 10);
            cvt_hilo(x3, hh, ll);
            *(ushort4*)&Xbf[rb + colg*4] = hh;  *(ushort4*)&Xbf[rb + 512 + colg*4] = ll;
        }
        float r0s = f4sum(x0), r1s = f4sum(x1), r2s = f4sum(x2), r3s = f4sum(x3);
        #pragma unroll
        for(int off = 32; off; off >>= 1){
            r0s += __shfl_xor(r0s, off); r1s += __shfl_xor(r1s, off);
            r2s += __shfl_xor(r2s, off); r3s += __shfl_xor(r3s, off);
        }
        if(lane == 0){
            row_sums2[(b*LPAD + r   )*2 + h] = r0s;
            row_sums2[(b*LPAD + r+4 )*2 + h] = r1s;
            row_sums2[(b*LPAD + r+8 )*2 + h] = r2s;
            row_sums2[(b*LPAD + r+12)*2 + h] = r3s;
        }
    }
    for(; r < nsb; r += 4){
        int n = sidx[r];
        float l = slabf[r];
        float4 x = X4[(size_t)n*128 + colg];
        sa = f4add(sa, x);
        sp = f4fma(l, x, sp);
        {
            ushort4 hh, ll;
            size_t rb = ((size_t)(b*NS_CAP + r) << 10);
            cvt_hilo(x, hh, ll);
            *(ushort4*)&Xbf[rb + colg*4] = hh;  *(ushort4*)&Xbf[rb + 512 + colg*4] = ll;
        }
        float rs = f4sum(x);
        #pragma unroll
        for(int off = 32; off; off >>= 1) rs += __shfl_xor(rs, off);
        if(lane == 0) row_sums2[(b*LPAD + r)*2 + h] = rs;
    }
    // zero-pad Xbf rows [nsb, ceil64(nsb)) so k_gram's staged tails are finite
    {
        const int padf = min((nsb + 63) & ~63, NS_CAP);
        ushort4 z; z.x = z.y = z.z = z.w = 0;
        for(int rz = nsb + wave; rz < padf; rz += 4){
            size_t rb = ((size_t)(b*NS_CAP + rz) << 10);
            *(ushort4*)&Xbf[rb + colg*4] = z;
            *(ushort4*)&Xbf[rb + 512 + colg*4] = z;
        }
    }
    pa[wave][lane] = sa;
    pp[wave][lane] = sp;
    __syncthreads();
    if(tid < 64){
        float4 A = f4add(f4add(pa[0][tid],pa[1][tid]), f4add(pa[2][tid],pa[3][tid]));
        float4 P = f4add(f4add(pp[0][tid],pp[1][tid]), f4add(pp[2][tid],pp[3][tid]));
        float4 Nn = make_float4(A.x-P.x, A.y-P.y, A.z-P.z, A.w-P.w);
        float ia = 1.f/(float)ns, ip = 1.f/(float)npos, in = 1.f/(float)nneg;
        int c = b*128 + h*64 + tid;
        ((float4*)task_mean)[c] = make_float4(A.x*ia, A.y*ia, A.z*ia, A.w*ia);
        ((float4*)pos_mean )[c] = make_float4(P.x*ip, P.y*ip, P.z*ip, P.w*ip);
        ((float4*)neg_mean )[c] = make_float4(Nn.x*in, Nn.y*in, Nn.z*in, Nn.w*in);
    }
}

// ---------------------------------------------------------------------------
// Kernel 2: Gram via bf16 MFMA, staging from precomputed Xbf with
// global_load_lds + XOR swizzle (unchanged).
// ---------------------------------------------------------------------------
__global__ __launch_bounds__(256) void k_gram(
        const unsigned short* __restrict__ Xbf,
        const int* __restrict__ counts, float* __restrict__ G0)
{
    const int bid = blockIdx.x;
    const int b   = bid / NPAIRS;
    int tp = bid % NPAIRS;
    int ti = 0;
    while((ti+1)*(ti+2)/2 <= tp) ti++;
    const int tj  = tp - ti*(ti+1)/2;          // ti >= tj
    const int tid = threadIdx.x;
    const int lane = tid & 63;
    const int wave = tid >> 6;

    const int ns  = counts[b*4 + 0];
    const int nsc = min(ns, NS_CAP);
    if(ti * GTILE >= nsc) return;
    const bool diag = (ti == tj);

    // planes (ushort idx): Ahi 0, Alo 4096, Bhi 8192, Blo 12288 (32768 B total)
    __shared__ __align__(16) unsigned short SM[4 * GTILE * 64];
    unsigned short* const SAh = SM;
    unsigned short* const SAl = SM + 4096;
    const unsigned short* Bh = diag ? SAh : (SM + 8192);
    const unsigned short* Bl = diag ? SAl : (SM + 12288);

    const int r8  = lane >> 3;                 // row within 8-row group (0..7)
    const int blk = lane & 7;                  // 16B block within row
    const int fr = lane & 15;
    const int fq = (lane >> 4) * 8;
    const int ry = (wave >> 1) * 32;
    const int cx = (wave & 1) * 32;

    floatx4 acc[2][2];
    acc[0][0] = (floatx4){0.f,0.f,0.f,0.f};
    acc[0][1] = (floatx4){0.f,0.f,0.f,0.f};
    acc[1][0] = (floatx4){0.f,0.f,0.f,0.f};
    acc[1][1] = (floatx4){0.f,0.f,0.f,0.f};

    const int xr = blk ^ r8;                   // source-side swizzle
    for(int k0 = 0; k0 < DDIM; k0 += KCH){
        __syncthreads();
        #pragma unroll
        for(int i = 0; i < 4; i++){
            int e  = wave*4 + i;
            int pl = e >> 3, g = e & 7;
            int row = g*8 + r8;
            const unsigned short* src = Xbf
                + ((size_t)(b*NS_CAP + ti*GTILE + row) << 10)
                + pl*512 + k0 + (xr << 3);
            gload_lds16(src, SM + pl*4096 + row*64 + blk*8);
        }
        if(!diag){
            #pragma unroll
            for(int i = 0; i < 4; i++){
                int e  = wave*4 + i;
                int pl = e >> 3, g = e & 7;
                int row = g*8 + r8;
                const unsigned short* src = Xbf
                    + ((size_t)(b*NS_CAP + tj*GTILE + row) << 10)
                    + pl*512 + k0 + (xr << 3);
                gload_lds16(src, SM + 8192 + pl*4096 + row*64 + blk*8);
            }
        }
        __syncthreads();
        #pragma unroll
        for(int ks = 0; ks < KCH; ks += 32){
            const int j  = (ks + fq) >> 3;
            const int jx = (j ^ (fr & 7)) << 3; // swizzled ushort offset in row
            bf16x8 ah0 = *(const bf16x8*)&SAh[(ry      + fr)*64 + jx];
            bf16x8 ah1 = *(const bf16x8*)&SAh[(ry + 16 + fr)*64 + jx];
            bf16x8 al0 = *(const bf16x8*)&SAl[(ry      + fr)*64 + jx];
            bf16x8 al1 = *(const bf16x8*)&SAl[(ry + 16 + fr)*64 + jx];
            bf16x8 bh0 = *(const bf16x8*)&Bh [(cx      + fr)*64 + jx];
            bf16x8 bh1 = *(const bf16x8*)&Bh [(cx + 16 + fr)*64 + jx];
            bf16x8 bl0 = *(const bf16x8*)&Bl [(cx      + fr)*64 + jx];
            bf16x8 bl1 = *(const bf16x8*)&Bl [(cx + 16 + fr)*64 + jx];
            acc[0][0] = __builtin_amdgcn_mfma_f32_16x16x32_bf16(ah0, bh0, acc[0][0], 0,0,0);
            acc[0][1] = __builtin_amdgcn_mfma_f32_16x16x32_bf16(ah0, bh1, acc[0][1], 0,0,0);
            acc[1][0] = __builtin_amdgcn_mfma_f32_16x16x32_bf16(ah1, bh0, acc[1][0], 0,0,0);
            acc[1][1] = __builtin_amdgcn_mfma_f32_16x16x32_bf16(ah1, bh1, acc[1][1], 0,0,0);
            acc[0][0] = __builtin_amdgcn_mfma_f32_16x16x32_bf16(ah0, bl0, acc[0][0], 0,0,0);
            acc[0][1] = __builtin_amdgcn_mfma_f32_16x16x32_bf16(ah0, bl1, acc[0][1], 0,0,0);
            acc[1][0] = __builtin_amdgcn_mfma_f32_16x16x32_bf16(ah1, bl0, acc[1][0], 0,0,0);
            acc[1][1] = __builtin_amdgcn_mfma_f32_16x16x32_bf16(ah1, bl1, acc[1][1], 0,0,0);
            acc[0][0] = __builtin_amdgcn_mfma_f32_16x16x32_bf16(al0, bh0, acc[0][0], 0,0,0);
            acc[0][1] = __builtin_amdgcn_mfma_f32_16x16x32_bf16(al0, bh1, acc[0][1], 0,0,0);
            acc[1][0] = __builtin_amdgcn_mfma_f32_16x16x32_bf16(al1, bh0, acc[1][0], 0,0,0);
            acc[1][1] = __builtin_amdgcn_mfma_f32_16x16x32_bf16(al1, bh1, acc[1][1], 0,0,0);
        }
    }

    float4* Gf4 = (float4*)(G0 + (size_t)b * NS_CAP * NS_CAP);
    const int q = lane >> 4, j = lane & 15;
    #pragma unroll
    for(int sy = 0; sy < 2; sy++)
        #pragma unroll
        for(int sx = 0; sx < 2; sx++){
            int cq = ((ti*GTILE + ry + sy*16) >> 2) + q;
            int t  = tj*GTILE + cx + sx*16 + j;
            Gf4[(size_t)cq * NS_CAP + t] =
                make_float4(acc[sy][sx].x, acc[sy][sx].y, acc[sy][sx].z, acc[sy][sx].w);
        }

    if(!diag){
        __syncthreads();
        float* Tb = (float*)SM;                // 64 x 68 floats = 17408 B <= 32768
        #pragma unroll
        for(int sy = 0; sy < 2; sy++)
            #pragma unroll
            for(int sx = 0; sx < 2; sx++){
                int r0 = ry + sy*16 + 4*q;
                int c  = cx + sx*16 + j;
                Tb[(r0+0)*68 + c] = acc[sy][sx].x;
                Tb[(r0+1)*68 + c] = acc[sy][sx].y;
                Tb[(r0+2)*68 + c] = acc[sy][sx].z;
                Tb[(r0+3)*68 + c] = acc[sy][sx].w;
            }
        __syncthreads();
        for(int e = tid; e < 16*GTILE; e += 256){
            int cc = e >> 6;
            int r  = e & 63;
            float4 v = *(const float4*)&Tb[r*68 + 4*cc];
            Gf4[(size_t)(tj*16 + cc) * NS_CAP + ti*GTILE + r] = v;
        }
    }
}

// ---------------------------------------------------------------------------
// Kernel 3: coefficient-space CG + fused query output.
// v10: amdgpu_waves_per_eu(2,2) — BOTH min and max pinned to 2 waves/EU.
// v9's __launch_bounds__(512,2) only set the MIN (permits 256 VGPR but the
// allocator's occupancy heuristic still capped at 128 and spilled g[], since
// dynamic LDS size is invisible at compile time). With max=2 there is no
// occupancy benefit below 256 VGPRs, so the allocator keeps g[48] (192 VGPR)
// in registers. No other changes.
// ---------------------------------------------------------------------------
extern __shared__ float4 gl4[];                // GL_F4 float4 (65536 B)

__global__ __launch_bounds__(512)
__attribute__((amdgpu_waves_per_eu(2, 2)))
void k_cgc(
        const float* __restrict__ X, const float* __restrict__ G0,
        const int* __restrict__ sup_idx, const int* __restrict__ sup_lab,
        const int* __restrict__ counts, const float* __restrict__ row_sums2,
        const int* __restrict__ qry_idx,
        const float* __restrict__ pos_mean, const float* __restrict__ neg_mean,
        const float* __restrict__ log_scale, float* __restrict__ out)
{
    const int bid  = blockIdx.x;
    const int sys  = ((bid & 7) << 5) | (bid >> 3);   // pair-local XCD swizzle
    const int b    = sys >> 1;
    const int cls  = sys & 1;
    const int tid  = threadIdx.x;
    const int lane = tid & 63;
    const int wave = tid >> 6;

    __shared__ __align__(16) float u[NS_CAP];
    __shared__ int   idx_l[NS_CAP];
    __shared__ int   qidx_l[LPAD];
    __shared__ float P[64];                    // [wave*8 + k], k<5 valid
    __shared__ __align__(16) float4 vv[128];   // solved v (D=512)

    const int ns   = counts[b*4 + 0];
    const int nsc  = min(ns, NS_CAP);
    const int nq   = counts[b*4 + 1];
    const int nqc  = min(nq, LPAD);
    const int ncls = cls ? counts[b*4 + 2] : counts[b*4 + 3];
    const float c_task = 0.9f / (float)(ns - 1);
    const float c_cls  = 0.1f / (float)(ncls - 1);
    const float inv_ns = 1.f / (float)ns;
    const float inv_nc = 1.f / (float)ncls;
    const float4* G4 = (const float4*)(G0 + (size_t)b * NS_CAP * NS_CAP);
    const float4* u4 = (const float4*)u;
    const int nf4 = (nsc + 3) >> 2;

    const bool mth = tid < NS_CAP;
    const bool own = tid < nsc;
    float mfl = 0.f, sraw = 0.f;
    if(own){
        mfl  = (sup_lab[b*LPAD + tid] == cls) ? 1.f : 0.f;
        float2 rs = ((const float2*)row_sums2)[b*LPAD + tid];
        sraw = rs.x + rs.y;
    }
    for(int s = tid; s < nsc; s += 512) idx_l[s] = sup_idx[b*LPAD + s];
    qidx_l[tid] = qry_idx[b*LPAD + tid];       // 512 threads cover LPAD exactly
    if(tid < 64) P[tid] = 0.f;                 // zero pad slots (k>=5)

    const bool fastu   = (nf4 <= 64);          // nsc <= 256 (always, in practice)
    const bool haverow = ((wave << 6) < nsc);  // wave-uniform: wave owns >=1 row

    // Register-resident Gram row: g[c4] = G4[c4*NS_CAP + tid], zero-masked for
    // columns >= nsc. Fully unrolled, compile-time indices -> promoted to VGPRs.
    float4 g[GREG];
    if(fastu && haverow){
        #pragma unroll
        for(int c4 = 0; c4 < GREG; c4++){
            float4 v = G4[(size_t)c4 * NS_CAP + tid];
            bool live = (4*c4 < nsc);
            g[c4].x = live ? v.x : 0.f;
            g[c4].y = live ? v.y : 0.f;
            g[c4].z = live ? v.z : 0.f;
            g[c4].w = live ? v.w : 0.f;
        }
    }

    // Spill columns (GREG <= c4 < nf4, only when nsc > 4*GREG=192): stage once.
    if(fastu && nf4 > GREG){
        const int nchunk = (nsc + 63) >> 6;
        for(int ch = 0; ch < nchunk; ch++){
            const int t = (ch << 6) + lane;
            const bool act = t < nsc;
            for(int c4 = GREG + wave; c4 < nf4; c4 += 8){
                if(act) gload_lds16(G4 + (size_t)c4 * NS_CAP + t,
                                    gl4 + (c4 - GREG) * nsc + t);
            }
        }
    }
    __syncthreads();   // orders P-zero before bundle's P writes; drains staging

    auto bundle = [&](float v0, float v1, float v2, float v3, float v4,
                      float* S){
        #pragma unroll
        for(int off = 32; off; off >>= 1){
            v0 += __shfl_xor(v0, off); v1 += __shfl_xor(v1, off);
            v2 += __shfl_xor(v2, off); v3 += __shfl_xor(v3, off);
            v4 += __shfl_xor(v4, off);
        }
        if(lane == 0){
            P[wave*8 + 0] = v0; P[wave*8 + 1] = v1; P[wave*8 + 2] = v2;
            P[wave*8 + 3] = v3; P[wave*8 + 4] = v4;
        }
        __syncthreads();                       // (a)
        float pv = P[lane];
        pv += __shfl_xor(pv, 8);
        pv += __shfl_xor(pv, 16);
        pv += __shfl_xor(pv, 32);              // pv = S[lane & 7]
        S[0] = __shfl(pv, 0); S[1] = __shfl(pv, 1); S[2] = __shfl(pv, 2);
        S[3] = __shfl(pv, 3); S[4] = __shfl(pv, 4);
    };

    auto matvec = [&]() -> float {
        float t = 0.f;
        if(fastu){
            if(haverow){
                // one ds_read_b128 per wave: lane l caches u4[l]; all 64 lanes
                // execute (wave-uniform guard), pinned against sinking.
                float4 ubc = u4[lane < nf4 ? lane : 0];
                asm volatile("" : "+v"(ubc.x), "+v"(ubc.y), "+v"(ubc.z), "+v"(ubc.w));
                float s0 = 0.f, s1 = 0.f, s2 = 0.f, s3 = 0.f;
                #pragma unroll
                for(int c4 = 0; c4 < GREG; c4 += 4){
                    s0 += dotb(g[c4+0], ubc, c4+0);
                    s1 += dotb(g[c4+1], ubc, c4+1);
                    s2 += dotb(g[c4+2], ubc, c4+2);
                    s3 += dotb(g[c4+3], ubc, c4+3);
                }
                // spill columns from LDS (rare; u broadcast via LDS read)
                if(nf4 > GREG){
                    const int row = own ? tid : (nsc - 1);
                    for(int c4 = GREG; c4 < nf4; c4++)
                        s0 += f4dot(gl4[(c4 - GREG)*nsc + row], u4[c4]);
                }
                t = (s0 + s1) + (s2 + s3);
            }
            return own ? t : 0.f;
        } else {
            // fallback (nsc > 256; does not occur for this input): global reads
            float s0 = 0.f, s1 = 0.f, s2 = 0.f, s3 = 0.f;
            if(own){
                int c4 = 0;
                for(; c4 + 4 <= nf4; c4 += 4){
                    float4 h0 = G4[(size_t)(c4+0)*NS_CAP + tid];
                    float4 h1 = G4[(size_t)(c4+1)*NS_CAP + tid];
                    float4 h2 = G4[(size_t)(c4+2)*NS_CAP + tid];
                    float4 h3 = G4[(size_t)(c4+3)*NS_CAP + tid];
                    s0 += f4dot(h0, u4[c4+0]); s1 += f4dot(h1, u4[c4+1]);
                    s2 += f4dot(h2, u4[c4+2]); s3 += f4dot(h3, u4[c4+3]);
                }
                for(; c4 < nf4; c4++) s0 += f4dot(G4[(size_t)c4*NS_CAP + tid], u4[c4]);
            }
            float tt = (s0 + s1) + (s2 + s3);
            return own ? tt : 0.f;
        }
    };

    // init: r0 = -10 * A * 1  (t-image of p=1_D is the row-sum vector)
    float S[5];
    bundle(sraw, mfl * sraw, 0.f, 0.f, 0.f, S);
    float A0 = S[0] * inv_ns, A1 = S[1] * inv_nc;
    float cr = own ? -10.f * (c_task*(sraw - A0) + mfl*c_cls*(sraw - A1)) : 0.f;
    if(mth) u[tid] = cr;                       // cr = 0 for !own
    __syncthreads();                           // (b)
    float tr = matvec();

    float cp = 0.f, cq = 0.f, tq = 0.f, cx = 0.f;
    float gamma_old = 1.f, alpha_old = 1.f;
    bool first = true;

    for(int it = 0; it < CG_ITERS; ++it){
        // bundle: S1=Σtr, S2=Σm·tr, S3=Σtr², S4=Σm·tr², S5=Σtr·cr
        bundle(tr, mfl*tr, tr*tr, mfl*tr*tr, tr*cr, S);
        A0 = S[0] * inv_ns; A1 = S[1] * inv_nc;
        float gamma = S[4];                                  // (r,r)
        float delta = 0.1f*gamma + c_task*(S[2] - S[0]*A0)
                                 + c_cls *(S[3] - S[1]*A1);  // (r,Mr)
        float beta  = first ? 0.f : gamma / gamma_old;
        float denom = first ? delta : (delta - beta * gamma / alpha_old);
        float alpha = (gamma < 1e-30f) ? 0.f : gamma / denom;
        float ur = own ? (c_task*(tr - A0) + mfl*c_cls*(tr - A1)) : 0.f;
        float cw = 0.1f*cr + ur;                             // c of w = M r
        cp = cr + beta * cp;
        cq = cw + beta * cq;
        cx += alpha * cp;
        if(it == CG_ITERS - 1 || gamma < 1e-26f) break;      // final sweep skipped
        if(mth) u[tid] = ur;
        __syncthreads();                                     // (b)
        float gv = matvec();                                 // G0 * u_r
        float tw = 0.1f*tr + gv;                             // t of w
        tq = tw + beta * tq;
        cr -= alpha * cq;
        tr -= alpha * tq;
        gamma_old = gamma; alpha_old = alpha; first = false;
    }

    // v = 10*1 + Xs^T c_x  (accumulated into vv[] in LDS)
    __syncthreads();
    if(mth) u[tid] = own ? cx : 0.f;
    __syncthreads();
    const float4* X4 = (const float4*)X;
    const int f4c = tid & 127;
    const int rg  = tid >> 7;
    float4 acc = make_float4(0.f,0.f,0.f,0.f);
    int s = rg;
    for(; s + 28 < nsc; s += 32){
        int n0 = idx_l[s],    n1 = idx_l[s+4],  n2 = idx_l[s+8],  n3 = idx_l[s+12];
        int n4 = idx_l[s+16], n5 = idx_l[s+20], n6 = idx_l[s+24], n7 = idx_l[s+28];
        float w0 = u[s],    w1 = u[s+4],  w2 = u[s+8],  w3 = u[s+12];
        float w4 = u[s+16], w5 = u[s+20], w6 = u[s+24], w7 = u[s+28];
        float4 x0 = X4[(size_t)n0*128 + f4c];
        float4 x1 = X4[(size_t)n1*128 + f4c];
        float4 x2 = X4[(size_t)n2*128 + f4c];
        float4 x3 = X4[(size_t)n3*128 + f4c];
        float4 x4 = X4[(size_t)n4*128 + f4c];
        float4 x5 = X4[(size_t)n5*128 + f4c];
        float4 x6 = X4[(size_t)n6*128 + f4c];
        float4 x7 = X4[(size_t)n7*128 + f4c];
        acc = f4fma(w0,x0, f4fma(w1,x1, f4fma(w2,x2, f4fma(w3,x3, acc))));
        acc = f4fma(w4,x4, f4fma(w5,x5, f4fma(w6,x6, f4fma(w7,x7, acc))));
    }
    for(; s < nsc; s += 4)
        acc = f4fma(u[s], X4[(size_t)idx_l[s]*128 + f4c], acc);
    gl4[rg*128 + f4c] = acc;
    __syncthreads();
    if(tid < 128){
        float4 v = f4add(f4add(gl4[tid], gl4[128+tid]),
                         f4add(gl4[256+tid], gl4[384+tid]));
        v.x += 10.f; v.y += 10.f; v.z += 10.f; v.w += 10.f;
        vv[tid] = v;
    }

    // sm = sum(mean_c), mv = mean_c . v  (one bundle; vv made visible by its
    // internal barrier — each tid<128 reads only its own vv element here)
    const float* mean_c = cls ? pos_mean : neg_mean;
    float psm = 0.f, pmv = 0.f;
    if(tid < 128){
        float4 m4 = ((const float4*)mean_c)[b*128 + tid];
        float4 v  = vv[tid];
        psm = f4sum(m4);
        pmv = f4dot(m4, v);
    }
    bundle(psm, pmv, 0.f, 0.f, 0.f, S);
    const float sm = S[0], mv = S[1];
    const float scale = expf(log_scale[0]);

    // query loop: 8 waves, 2 rows per wave per iteration
    const float4 va = vv[lane], vb = vv[lane + 64];
    for(int r = wave; r < nqc; r += 16){
        int r2 = r + 8;
        bool has2 = r2 < nqc;
        int n  = qidx_l[r];
        int n2 = qidx_l[has2 ? r2 : r];
        const float4* xr = (const float4*)(X + (size_t)n  * DDIM);
        const float4* yr = (const float4*)(X + (size_t)n2 * DDIM);
        float4 x0 = xr[lane], x1 = xr[lane + 64];
        float4 y0 = yr[lane], y1 = yr[lane + 64];
        float t1 = f4dot(x0, va) + f4dot(x1, vb);
        float s1 = f4sum(x0) + f4sum(x1);
        float t2 = f4dot(y0, va) + f4dot(y1, vb);
        float s2 = f4sum(y0) + f4sum(y1);
        #pragma unroll
        for(int off = 32; off; off >>= 1){
            t1 += __shfl_xor(t1, off);
            s1 += __shfl_xor(s1, off);
            t2 += __shfl_xor(t2, off);
            s2 += __shfl_xor(s2, off);
        }
        if(lane == 0){
            out[(size_t)(b*LPAD + r)*2 + cls] = (t1 - mv) * (s1 - sm) * scale;
            if(has2)
                out[(size_t)(b*LPAD + r2)*2 + cls] = (t2 - mv) * (s2 - sm) * scale;
        }
    }
    for(int r = nqc + tid; r < LPAD; r += 512)
        out[(size_t)(b*LPAD + r)*2 + cls] = 0.f;
}

// ---------------------------------------------------------------------------
extern "C" void kernel_launch(void* const* d_in, const int* in_sizes, int n_in,
                              void* d_out, int out_size, void* d_ws, size_t ws_size,
                              hipStream_t stream)
{
    const float* X         = (const float*)d_in[0];
    const float* log_scale = (const float*)d_in[1];
    const int*   labels    = (const int*)d_in[2];
    const int*   is_query  = (const int*)d_in[3];
    const int*   bidx      = (const int*)d_in[4];
    const int N = in_sizes[2];

    char* ws = (char*)d_ws;
    auto alloc = [&](size_t bytes) -> char* {
        char* p = ws;
        ws += (bytes + 255) & ~(size_t)255;
        return p;
    };
    int*   sup_idx   = (int*)  alloc((size_t)EPISODES * LPAD * sizeof(int));
    int*   qry_idx   = (int*)  alloc((size_t)EPISODES * LPAD * sizeof(int));
    int*   sup_lab   = (int*)  alloc((size_t)EPISODES * LPAD * sizeof(int));
    int*   counts    = (int*)  alloc((size_t)EPISODES * 4 * sizeof(int));
    float* task_mean = (float*)alloc((size_t)EPISODES * DDIM * sizeof(float));
    float* pos_mean  = (float*)alloc((size_t)EPISODES * DDIM * sizeof(float));
    float* neg_mean  = (float*)alloc((size_t)EPISODES * DDIM * sizeof(float));
    float* row_sums2 = (float*)alloc((size_t)EPISODES * LPAD * 2 * sizeof(float));
    float* G0        = (float*)alloc((size_t)EPISODES * NS_CAP * NS_CAP * sizeof(float));
    unsigned short* Xbf = (unsigned short*)alloc(
                          (size_t)EPISODES * NS_CAP * XBF_ROW * sizeof(unsigned short));
    (void)ws_size;
    (void)task_mean;

    k_prep<<<EPISODES*2, 256, 0, stream>>>(labels, is_query, bidx, X, N,
                                           sup_idx, qry_idx, sup_lab, counts,
                                           task_mean, pos_mean, neg_mean, row_sums2,
                                           Xbf);
    k_gram<<<EPISODES * NPAIRS, 256, 0, stream>>>(Xbf, counts, G0);
    k_cgc<<<EPISODES * 2, 512, GL_F4 * sizeof(float4), stream>>>(
                                            X, G0, sup_idx, sup_lab, counts,
                                            row_sums2, qry_idx, pos_mean, neg_mean,
                                            log_scale, (float*)d_out);
}

// Round 9
// 264.766 us; speedup vs baseline: 1.0363x; 1.0350x over previous
//
#include <hip/hip_runtime.h>
#include <cstdint>
#include <cstddef>

#define EPISODES 128
#define LPAD     512
#define DDIM     512
#define NS_CAP   320
#define GTILE    64
#define NPAIRS   15          // 5*(5+1)/2 tile pairs (NS_CAP/GTILE = 5)
#define CG_ITERS 14
#define GL_F4    9216        // dynamic-LDS float4 capacity (147456 B)
#define KCH      64          // k per staged chunk in k_gram
#define XBF_ROW  1024        // ushorts per Xbf row: 512 hi + 512 lo
#define GREG     24          // Gram row float4s held in registers per thread (96 VGPR)

typedef __attribute__((ext_vector_type(8))) __bf16 bf16x8;
typedef __attribute__((ext_vector_type(4))) float  floatx4;

__device__ __forceinline__ int lower_bound_dev(const int* __restrict__ a, int n, int key){
    int lo = 0, hi = n;
    while(lo < hi){
        int m = (lo + hi) >> 1;
        if(a[m] < key) lo = m + 1; else hi = m;
    }
    return lo;
}

__device__ __forceinline__ float4 f4add(float4 a, float4 b){
    return make_float4(a.x+b.x, a.y+b.y, a.z+b.z, a.w+b.w);
}
__device__ __forceinline__ float4 f4fma(float s, float4 a, float4 acc){
    return make_float4(acc.x + s*a.x, acc.y + s*a.y, acc.z + s*a.z, acc.w + s*a.w);
}
__device__ __forceinline__ float f4dot(float4 a, float4 b){
    return a.x*b.x + a.y*b.y + a.z*b.z + a.w*b.w;
}
__device__ __forceinline__ float f4sum(float4 a){ return (a.x+a.y)+(a.z+a.w); }

__device__ __forceinline__ unsigned short f2bf(float x){
    unsigned u = __float_as_uint(x);
    u += 0x7FFFu + ((u >> 16) & 1u);
    return (unsigned short)(u >> 16);
}
__device__ __forceinline__ float bf2f(unsigned short h){
    return __uint_as_float(((unsigned)h) << 16);
}
__device__ __forceinline__ void cvt_hilo(float4 x, ushort4& hh, ushort4& ll){
    hh.x = f2bf(x.x); ll.x = f2bf(x.x - bf2f(hh.x));
    hh.y = f2bf(x.y); ll.y = f2bf(x.y - bf2f(hh.y));
    hh.z = f2bf(x.z); ll.z = f2bf(x.z - bf2f(hh.z));
    hh.w = f2bf(x.w); ll.w = f2bf(x.w - bf2f(hh.w));
}

// wave-uniform-index register broadcast (v_readlane -> SGPR operand)
__device__ __forceinline__ float rdlanef(float v, int l){
    return __int_as_float(__builtin_amdgcn_readlane(__float_as_int(v), l));
}
__device__ __forceinline__ float dotb(float4 g, float4 u, int l){
    return g.x*rdlanef(u.x,l) + g.y*rdlanef(u.y,l)
         + g.z*rdlanef(u.z,l) + g.w*rdlanef(u.w,l);
}
// async 16B/lane global->LDS (linear dest = first-active-lane base + lane*16)
__device__ __forceinline__ void gload_lds16(const void* g, void* l){
    __builtin_amdgcn_global_load_lds(
        (const __attribute__((address_space(1))) void*)g,
        (__attribute__((address_space(3))) void*)l,
        16, 0, 0);
}

// ---------------------------------------------------------------------------
// Kernel 1: fused segmentation + means + per-half row sums + Xbf emission
// (unchanged).
// ---------------------------------------------------------------------------
__global__ __launch_bounds__(256) void k_prep(
        const int* __restrict__ labels, const int* __restrict__ is_query,
        const int* __restrict__ bidx, const float* __restrict__ X, int N,
        int* __restrict__ sup_idx, int* __restrict__ qry_idx,
        int* __restrict__ sup_lab, int* __restrict__ counts,
        float* __restrict__ task_mean, float* __restrict__ pos_mean,
        float* __restrict__ neg_mean, float* __restrict__ row_sums2,
        unsigned short* __restrict__ Xbf)
{
    const int bid  = blockIdx.x;
    const int b    = bid >> 1;
    const int h    = bid & 1;
    const int tid  = threadIdx.x;
    const int lane = tid & 63;
    const int wave = tid >> 6;

    __shared__ int s_start, s_end;
    __shared__ int wq[4];
    __shared__ int s_runq, s_npos;
    __shared__ int   sidx[NS_CAP];
    __shared__ float slabf[NS_CAP];
    __shared__ float4 pa[4][64];
    __shared__ float4 pp[4][64];

    if(tid == 0){
        s_start = lower_bound_dev(bidx, N, b);
        s_end   = lower_bound_dev(bidx, N, b + 1);
        s_runq  = 0;
        s_npos  = 0;
    }
    __syncthreads();
    const int start = s_start, end = s_end;

    for(int base = start; base < end; base += 256){
        int idx   = base + tid;
        bool valid = idx < end;
        int q   = valid ? is_query[idx] : 0;
        int lab = valid ? labels[idx]   : 0;
        unsigned long long m = __ballot(q == 1);
        if(lane == 0) wq[wave] = __popcll(m);
        __syncthreads();
        int woff = 0;
        for(int w = 0; w < wave; w++) woff += wq[w];
        int qbefore = __popcll(m & ((1ull << lane) - 1ull)) + woff;
        int runq0 = s_runq;
        int chunk_total = wq[0] + wq[1] + wq[2] + wq[3];
        if(valid){
            int pos_in_seg = idx - start;
            if(q){
                int qr = runq0 + qbefore;
                if(h == 0 && qr < LPAD) qry_idx[b * LPAD + qr] = idx;
            } else {
                int sr = pos_in_seg - runq0 - qbefore;
                if(sr < LPAD){
                    if(h == 0){
                        sup_idx[b * LPAD + sr] = idx;
                        sup_lab[b * LPAD + sr] = lab;
                    }
                    if(sr < NS_CAP){ sidx[sr] = idx; slabf[sr] = (float)lab; }
                    if(lab == 1) atomicAdd(&s_npos, 1);
                }
            }
        }
        __syncthreads();
        if(tid == 0) s_runq = runq0 + chunk_total;
        __syncthreads();
    }

    const int nq   = s_runq;
    const int ns   = (end - start) - nq;
    const int npos = s_npos;
    const int nneg = ns - npos;
    if(h == 0 && tid == 0){
        counts[b*4 + 0] = ns;
        counts[b*4 + 1] = nq;
        counts[b*4 + 2] = npos;
        counts[b*4 + 3] = nneg;
    }
    const int nsb = min(ns, NS_CAP);

    const float4* X4 = (const float4*)X;
    const int colg = h*64 + lane;            // float4 index in [0,128)
    float4 sa = make_float4(0.f,0.f,0.f,0.f);
    float4 sp = make_float4(0.f,0.f,0.f,0.f);
    int r = wave;
    for(; r + 12 < nsb; r += 16){
        int n0 = sidx[r], n1 = sidx[r+4], n2 = sidx[r+8], n3 = sidx[r+12];
        float l0 = slabf[r], l1 = slabf[r+4], l2 = slabf[r+8], l3 = slabf[r+12];
        float4 x0 = X4[(size_t)n0*128 + colg];
        float4 x1 = X4[(size_t)n1*128 + colg];
        float4 x2 = X4[(size_t)n2*128 + colg];
        float4 x3 = X4[(size_t)n3*128 + colg];
        sa = f4add(sa, f4add(f4add(x0,x1), f4add(x2,x3)));
        sp = f4fma(l0,x0, f4fma(l1,x1, f4fma(l2,x2, f4fma(l3,x3, sp))));
        {
            ushort4 hh, ll;
            size_t rb;
            rb = ((size_t)(b*NS_CAP + r   ) << 10);
            cvt_hilo(x0, hh, ll);
            *(ushort4*)&Xbf[rb + colg*4] = hh;  *(ushort4*)&Xbf[rb + 512 + colg*4] = ll;
            rb = ((size_t)(b*NS_CAP + r+4 ) << 10);
            cvt_hilo(x1, hh, ll);
            *(ushort4*)&Xbf[rb + colg*4] = hh;  *(ushort4*)&Xbf[rb + 512 + colg*4] = ll;
            rb = ((size_t)(b*NS_CAP + r+8 ) << 10);
            cvt_hilo(x2, hh, ll);
            *(ushort4*)&Xbf[rb + colg*4] = hh;  *(ushort4*)&Xbf[rb + 512 + colg*4] = ll;
            rb = ((size_t)(b*NS_CAP + r+12) << 10);
            cvt_hilo(x3, hh, ll);
            *(ushort4*)&Xbf[rb + colg*4] = hh;  *(ushort4*)&Xbf[rb + 512 + colg*4] = ll;
        }
        float r0s = f4sum(x0), r1s = f4sum(x1), r2s = f4sum(x2), r3s = f4sum(x3);
        #pragma unroll
        for(int off = 32; off; off >>= 1){
            r0s += __shfl_xor(r0s, off); r1s += __shfl_xor(r1s, off);
            r2s += __shfl_xor(r2s, off); r3s += __shfl_xor(r3s, off);
        }
        if(lane == 0){
            row_sums2[(b*LPAD + r   )*2 + h] = r0s;
            row_sums2[(b*LPAD + r+4 )*2 + h] = r1s;
            row_sums2[(b*LPAD + r+8 )*2 + h] = r2s;
            row_sums2[(b*LPAD + r+12)*2 + h] = r3s;
        }
    }
    for(; r < nsb; r += 4){
        int n = sidx[r];
        float l = slabf[r];
        float4 x = X4[(size_t)n*128 + colg];
        sa = f4add(sa, x);
        sp = f4fma(l, x, sp);
        {
            ushort4 hh, ll;
            size_t rb = ((size_t)(b*NS_CAP + r) << 10);
            cvt_hilo(x, hh, ll);
            *(ushort4*)&Xbf[rb + colg*4] = hh;  *(ushort4*)&Xbf[rb + 512 + colg*4] = ll;
        }
        float rs = f4sum(x);
        #pragma unroll
        for(int off = 32; off; off >>= 1) rs += __shfl_xor(rs, off);
        if(lane == 0) row_sums2[(b*LPAD + r)*2 + h] = rs;
    }
    // zero-pad Xbf rows [nsb, ceil64(nsb)) so k_gram's staged tails are finite
    {
        const int padf = min((nsb + 63) & ~63, NS_CAP);
        ushort4 z; z.x = z.y = z.z = z.w = 0;
        for(int rz = nsb + wave; rz < padf; rz += 4){
            size_t rb = ((size_t)(b*NS_CAP + rz) << 10);
            *(ushort4*)&Xbf[rb + colg*4] = z;
            *(ushort4*)&Xbf[rb + 512 + colg*4] = z;
        }
    }
    pa[wave][lane] = sa;
    pp[wave][lane] = sp;
    __syncthreads();
    if(tid < 64){
        float4 A = f4add(f4add(pa[0][tid],pa[1][tid]), f4add(pa[2][tid],pa[3][tid]));
        float4 P = f4add(f4add(pp[0][tid],pp[1][tid]), f4add(pp[2][tid],pp[3][tid]));
        float4 Nn = make_float4(A.x-P.x, A.y-P.y, A.z-P.z, A.w-P.w);
        float ia = 1.f/(float)ns, ip = 1.f/(float)npos, in = 1.f/(float)nneg;
        int c = b*128 + h*64 + tid;
        ((float4*)task_mean)[c] = make_float4(A.x*ia, A.y*ia, A.z*ia, A.w*ia);
        ((float4*)pos_mean )[c] = make_float4(P.x*ip, P.y*ip, P.z*ip, P.w*ip);
        ((float4*)neg_mean )[c] = make_float4(Nn.x*in, Nn.y*in, Nn.z*in, Nn.w*in);
    }
}

// ---------------------------------------------------------------------------
// Kernel 2: Gram via bf16 MFMA, staging from precomputed Xbf with
// global_load_lds + XOR swizzle (unchanged).
// ---------------------------------------------------------------------------
__global__ __launch_bounds__(256) void k_gram(
        const unsigned short* __restrict__ Xbf,
        const int* __restrict__ counts, float* __restrict__ G0)
{
    const int bid = blockIdx.x;
    const int b   = bid / NPAIRS;
    int tp = bid % NPAIRS;
    int ti = 0;
    while((ti+1)*(ti+2)/2 <= tp) ti++;
    const int tj  = tp - ti*(ti+1)/2;          // ti >= tj
    const int tid = threadIdx.x;
    const int lane = tid & 63;
    const int wave = tid >> 6;

    const int ns  = counts[b*4 + 0];
    const int nsc = min(ns, NS_CAP);
    if(ti * GTILE >= nsc) return;
    const bool diag = (ti == tj);

    // planes (ushort idx): Ahi 0, Alo 4096, Bhi 8192, Blo 12288 (32768 B total)
    __shared__ __align__(16) unsigned short SM[4 * GTILE * 64];
    unsigned short* const SAh = SM;
    unsigned short* const SAl = SM + 4096;
    const unsigned short* Bh = diag ? SAh : (SM + 8192);
    const unsigned short* Bl = diag ? SAl : (SM + 12288);

    const int r8  = lane >> 3;                 // row within 8-row group (0..7)
    const int blk = lane & 7;                  // 16B block within row
    const int fr = lane & 15;
    const int fq = (lane >> 4) * 8;
    const int ry = (wave >> 1) * 32;
    const int cx = (wave & 1) * 32;

    floatx4 acc[2][2];
    acc[0][0] = (floatx4){0.f,0.f,0.f,0.f};
    acc[0][1] = (floatx4){0.f,0.f,0.f,0.f};
    acc[1][0] = (floatx4){0.f,0.f,0.f,0.f};
    acc[1][1] = (floatx4){0.f,0.f,0.f,0.f};

    const int xr = blk ^ r8;                   // source-side swizzle
    for(int k0 = 0; k0 < DDIM; k0 += KCH){
        __syncthreads();
        #pragma unroll
        for(int i = 0; i < 4; i++){
            int e  = wave*4 + i;
            int pl = e >> 3, g = e & 7;
            int row = g*8 + r8;
            const unsigned short* src = Xbf
                + ((size_t)(b*NS_CAP + ti*GTILE + row) << 10)
                + pl*512 + k0 + (xr << 3);
            gload_lds16(src, SM + pl*4096 + row*64 + blk*8);
        }
        if(!diag){
            #pragma unroll
            for(int i = 0; i < 4; i++){
                int e  = wave*4 + i;
                int pl = e >> 3, g = e & 7;
                int row = g*8 + r8;
                const unsigned short* src = Xbf
                    + ((size_t)(b*NS_CAP + tj*GTILE + row) << 10)
                    + pl*512 + k0 + (xr << 3);
                gload_lds16(src, SM + 8192 + pl*4096 + row*64 + blk*8);
            }
        }
        __syncthreads();
        #pragma unroll
        for(int ks = 0; ks < KCH; ks += 32){
            const int j  = (ks + fq) >> 3;
            const int jx = (j ^ (fr & 7)) << 3; // swizzled ushort offset in row
            bf16x8 ah0 = *(const bf16x8*)&SAh[(ry      + fr)*64 + jx];
            bf16x8 ah1 = *(const bf16x8*)&SAh[(ry + 16 + fr)*64 + jx];
            bf16x8 al0 = *(const bf16x8*)&SAl[(ry      + fr)*64 + jx];
            bf16x8 al1 = *(const bf16x8*)&SAl[(ry + 16 + fr)*64 + jx];
            bf16x8 bh0 = *(const bf16x8*)&Bh [(cx      + fr)*64 + jx];
            bf16x8 bh1 = *(const bf16x8*)&Bh [(cx + 16 + fr)*64 + jx];
            bf16x8 bl0 = *(const bf16x8*)&Bl [(cx      + fr)*64 + jx];
            bf16x8 bl1 = *(const bf16x8*)&Bl [(cx + 16 + fr)*64 + jx];
            acc[0][0] = __builtin_amdgcn_mfma_f32_16x16x32_bf16(ah0, bh0, acc[0][0], 0,0,0);
            acc[0][1] = __builtin_amdgcn_mfma_f32_16x16x32_bf16(ah0, bh1, acc[0][1], 0,0,0);
            acc[1][0] = __builtin_amdgcn_mfma_f32_16x16x32_bf16(ah1, bh0, acc[1][0], 0,0,0);
            acc[1][1] = __builtin_amdgcn_mfma_f32_16x16x32_bf16(ah1, bh1, acc[1][1], 0,0,0);
            acc[0][0] = __builtin_amdgcn_mfma_f32_16x16x32_bf16(ah0, bl0, acc[0][0], 0,0,0);
            acc[0][1] = __builtin_amdgcn_mfma_f32_16x16x32_bf16(ah0, bl1, acc[0][1], 0,0,0);
            acc[1][0] = __builtin_amdgcn_mfma_f32_16x16x32_bf16(ah1, bl0, acc[1][0], 0,0,0);
            acc[1][1] = __builtin_amdgcn_mfma_f32_16x16x32_bf16(ah1, bl1, acc[1][1], 0,0,0);
            acc[0][0] = __builtin_amdgcn_mfma_f32_16x16x32_bf16(al0, bh0, acc[0][0], 0,0,0);
            acc[0][1] = __builtin_amdgcn_mfma_f32_16x16x32_bf16(al0, bh1, acc[0][1], 0,0,0);
            acc[1][0] = __builtin_amdgcn_mfma_f32_16x16x32_bf16(al1, bh0, acc[1][0], 0,0,0);
            acc[1][1] = __builtin_amdgcn_mfma_f32_16x16x32_bf16(al1, bh1, acc[1][1], 0,0,0);
        }
    }

    float4* Gf4 = (float4*)(G0 + (size_t)b * NS_CAP * NS_CAP);
    const int q = lane >> 4, j = lane & 15;
    #pragma unroll
    for(int sy = 0; sy < 2; sy++)
        #pragma unroll
        for(int sx = 0; sx < 2; sx++){
            int cq = ((ti*GTILE + ry + sy*16) >> 2) + q;
            int t  = tj*GTILE + cx + sx*16 + j;
            Gf4[(size_t)cq * NS_CAP + t] =
                make_float4(acc[sy][sx].x, acc[sy][sx].y, acc[sy][sx].z, acc[sy][sx].w);
        }

    if(!diag){
        __syncthreads();
        float* Tb = (float*)SM;                // 64 x 68 floats = 17408 B <= 32768
        #pragma unroll
        for(int sy = 0; sy < 2; sy++)
            #pragma unroll
            for(int sx = 0; sx < 2; sx++){
                int r0 = ry + sy*16 + 4*q;
                int c  = cx + sx*16 + j;
                Tb[(r0+0)*68 + c] = acc[sy][sx].x;
                Tb[(r0+1)*68 + c] = acc[sy][sx].y;
                Tb[(r0+2)*68 + c] = acc[sy][sx].z;
                Tb[(r0+3)*68 + c] = acc[sy][sx].w;
            }
        __syncthreads();
        for(int e = tid; e < 16*GTILE; e += 256){
            int cc = e >> 6;
            int r  = e & 63;
            float4 v = *(const float4*)&Tb[r*68 + 4*cc];
            Gf4[(size_t)(tj*16 + cc) * NS_CAP + ti*GTILE + r] = v;
        }
    }
}

// ---------------------------------------------------------------------------
// Kernel 3: coefficient-space CG + fused query output.
// v11: GREG 48 -> 24. Two rounds (launch_bounds min-waves, waves_per_eu(2,2))
// failed to push the allocator past 128 VGPRs — it spilled g[48] regardless.
// Fix is deterministic: make the demand fit the budget. g[24] = 96 VGPR +
// ~30 live scalars ~= 125 <= 128 -> no spill by construction. The remaining
// ~26 Gram columns live in dynamic LDS (grown to 144 KB, async-staged via
// global_load_lds as in v4), read per-matvec with ds_read_b128 + readlane-
// broadcast u. 151 KB LDS -> 1 block/CU (grid == CU count, nothing lost).
// waves_per_eu attribute removed.
// ---------------------------------------------------------------------------
extern __shared__ float4 gl4[];                // GL_F4 float4 (147456 B)

__global__ __launch_bounds__(512) void k_cgc(
        const float* __restrict__ X, const float* __restrict__ G0,
        const int* __restrict__ sup_idx, const int* __restrict__ sup_lab,
        const int* __restrict__ counts, const float* __restrict__ row_sums2,
        const int* __restrict__ qry_idx,
        const float* __restrict__ pos_mean, const float* __restrict__ neg_mean,
        const float* __restrict__ log_scale, float* __restrict__ out)
{
    const int bid  = blockIdx.x;
    const int sys  = ((bid & 7) << 5) | (bid >> 3);   // pair-local XCD swizzle
    const int b    = sys >> 1;
    const int cls  = sys & 1;
    const int tid  = threadIdx.x;
    const int lane = tid & 63;
    const int wave = tid >> 6;

    __shared__ __align__(16) float u[NS_CAP];
    __shared__ int   idx_l[NS_CAP];
    __shared__ int   qidx_l[LPAD];
    __shared__ float P[64];                    // [wave*8 + k], k<5 valid
    __shared__ __align__(16) float4 vv[128];   // solved v (D=512)

    const int ns   = counts[b*4 + 0];
    const int nsc  = min(ns, NS_CAP);
    const int nq   = counts[b*4 + 1];
    const int nqc  = min(nq, LPAD);
    const int ncls = cls ? counts[b*4 + 2] : counts[b*4 + 3];
    const float c_task = 0.9f / (float)(ns - 1);
    const float c_cls  = 0.1f / (float)(ncls - 1);
    const float inv_ns = 1.f / (float)ns;
    const float inv_nc = 1.f / (float)ncls;
    const float4* G4 = (const float4*)(G0 + (size_t)b * NS_CAP * NS_CAP);
    const float4* u4 = (const float4*)u;
    const int nf4 = (nsc + 3) >> 2;

    const bool mth = tid < NS_CAP;
    const bool own = tid < nsc;
    float mfl = 0.f, sraw = 0.f;
    if(own){
        mfl  = (sup_lab[b*LPAD + tid] == cls) ? 1.f : 0.f;
        float2 rs = ((const float2*)row_sums2)[b*LPAD + tid];
        sraw = rs.x + rs.y;
    }
    for(int s = tid; s < nsc; s += 512) idx_l[s] = sup_idx[b*LPAD + s];
    qidx_l[tid] = qry_idx[b*LPAD + tid];       // 512 threads cover LPAD exactly
    if(tid < 64) P[tid] = 0.f;                 // zero pad slots (k>=5)

    const bool fastu   = (nf4 <= 64);          // nsc <= 256 (always, in practice)
    const bool haverow = ((wave << 6) < nsc);  // wave-uniform: wave owns >=1 row
    // LDS-resident columns: [GREG, c4lim); global fallback beyond (rare)
    const int c4lim = min(nf4, GREG + GL_F4 / max(nsc, 1));

    // Register-resident Gram row: g[c4] = G4[c4*NS_CAP + tid], c4 < 24.
    // Fully unrolled, compile-time indices -> promoted to VGPRs (96 VGPR).
    float4 g[GREG];
    if(fastu && haverow){
        #pragma unroll
        for(int c4 = 0; c4 < GREG; c4++){
            float4 v = G4[(size_t)c4 * NS_CAP + tid];
            bool live = (4*c4 < nsc);
            g[c4].x = live ? v.x : 0.f;
            g[c4].y = live ? v.y : 0.f;
            g[c4].z = live ? v.z : 0.f;
            g[c4].w = live ? v.w : 0.f;
        }
    }

    // Async-stage LDS-resident columns [GREG, c4lim): gl4[(c4-GREG)*nsc + t].
    if(fastu && c4lim > GREG){
        const int nchunk = (nsc + 63) >> 6;
        for(int ch = 0; ch < nchunk; ch++){
            const int t = (ch << 6) + lane;
            const bool act = t < nsc;
            for(int c4 = GREG + wave; c4 < c4lim; c4 += 8){
                if(act) gload_lds16(G4 + (size_t)c4 * NS_CAP + t,
                                    gl4 + (c4 - GREG) * nsc + t);
            }
        }
    }
    __syncthreads();   // orders P-zero before bundle's P writes; drains staging

    auto bundle = [&](float v0, float v1, float v2, float v3, float v4,
                      float* S){
        #pragma unroll
        for(int off = 32; off; off >>= 1){
            v0 += __shfl_xor(v0, off); v1 += __shfl_xor(v1, off);
            v2 += __shfl_xor(v2, off); v3 += __shfl_xor(v3, off);
            v4 += __shfl_xor(v4, off);
        }
        if(lane == 0){
            P[wave*8 + 0] = v0; P[wave*8 + 1] = v1; P[wave*8 + 2] = v2;
            P[wave*8 + 3] = v3; P[wave*8 + 4] = v4;
        }
        __syncthreads();                       // (a)
        float pv = P[lane];
        pv += __shfl_xor(pv, 8);
        pv += __shfl_xor(pv, 16);
        pv += __shfl_xor(pv, 32);              // pv = S[lane & 7]
        S[0] = __shfl(pv, 0); S[1] = __shfl(pv, 1); S[2] = __shfl(pv, 2);
        S[3] = __shfl(pv, 3); S[4] = __shfl(pv, 4);
    };

    auto matvec = [&]() -> float {
        float t = 0.f;
        if(fastu){
            if(haverow){
                // one ds_read_b128 per wave: lane l caches u4[l]; all 64 lanes
                // execute (wave-uniform guard), pinned against sinking.
                float4 ubc = u4[lane < nf4 ? lane : 0];
                asm volatile("" : "+v"(ubc.x), "+v"(ubc.y), "+v"(ubc.z), "+v"(ubc.w));
                float s0 = 0.f, s1 = 0.f, s2 = 0.f, s3 = 0.f;
                #pragma unroll
                for(int c4 = 0; c4 < GREG; c4 += 4){
                    s0 += dotb(g[c4+0], ubc, c4+0);
                    s1 += dotb(g[c4+1], ubc, c4+1);
                    s2 += dotb(g[c4+2], ubc, c4+2);
                    s3 += dotb(g[c4+3], ubc, c4+3);
                }
                // LDS-resident columns (tail lanes read row nsc-1: broadcast)
                const int row = own ? tid : (nsc - 1);
                const float4* gq = gl4 + row;
                int c4 = GREG;
                for(; c4 + 4 <= c4lim; c4 += 4){
                    float4 h0 = gq[(c4-GREG+0)*nsc];
                    float4 h1 = gq[(c4-GREG+1)*nsc];
                    float4 h2 = gq[(c4-GREG+2)*nsc];
                    float4 h3 = gq[(c4-GREG+3)*nsc];
                    s0 += dotb(h0, ubc, c4+0); s1 += dotb(h1, ubc, c4+1);
                    s2 += dotb(h2, ubc, c4+2); s3 += dotb(h3, ubc, c4+3);
                }
                for(; c4 < c4lim; c4++)
                    s0 += dotb(gq[(c4-GREG)*nsc], ubc, c4);
                // global fallback columns (only if LDS capacity exceeded)
                for(; c4 < nf4; c4++)
                    s0 += dotb(G4[(size_t)c4*NS_CAP + row], ubc, c4);
                t = (s0 + s1) + (s2 + s3);
            }
            return own ? t : 0.f;
        } else {
            // fallback (nsc > 256; does not occur for this input): global reads
            float s0 = 0.f, s1 = 0.f, s2 = 0.f, s3 = 0.f;
            if(own){
                int c4 = 0;
                for(; c4 + 4 <= nf4; c4 += 4){
                    float4 h0 = G4[(size_t)(c4+0)*NS_CAP + tid];
                    float4 h1 = G4[(size_t)(c4+1)*NS_CAP + tid];
                    float4 h2 = G4[(size_t)(c4+2)*NS_CAP + tid];
                    float4 h3 = G4[(size_t)(c4+3)*NS_CAP + tid];
                    s0 += f4dot(h0, u4[c4+0]); s1 += f4dot(h1, u4[c4+1]);
                    s2 += f4dot(h2, u4[c4+2]); s3 += f4dot(h3, u4[c4+3]);
                }
                for(; c4 < nf4; c4++) s0 += f4dot(G4[(size_t)c4*NS_CAP + tid], u4[c4]);
            }
            float tt = (s0 + s1) + (s2 + s3);
            return own ? tt : 0.f;
        }
    };

    // init: r0 = -10 * A * 1  (t-image of p=1_D is the row-sum vector)
    float S[5];
    bundle(sraw, mfl * sraw, 0.f, 0.f, 0.f, S);
    float A0 = S[0] * inv_ns, A1 = S[1] * inv_nc;
    float cr = own ? -10.f * (c_task*(sraw - A0) + mfl*c_cls*(sraw - A1)) : 0.f;
    if(mth) u[tid] = cr;                       // cr = 0 for !own
    __syncthreads();                           // (b)
    float tr = matvec();

    float cp = 0.f, cq = 0.f, tq = 0.f, cx = 0.f;
    float gamma_old = 1.f, alpha_old = 1.f;
    bool first = true;

    for(int it = 0; it < CG_ITERS; ++it){
        // bundle: S1=Σtr, S2=Σm·tr, S3=Σtr², S4=Σm·tr², S5=Σtr·cr
        bundle(tr, mfl*tr, tr*tr, mfl*tr*tr, tr*cr, S);
        A0 = S[0] * inv_ns; A1 = S[1] * inv_nc;
        float gamma = S[4];                                  // (r,r)
        float delta = 0.1f*gamma + c_task*(S[2] - S[0]*A0)
                                 + c_cls *(S[3] - S[1]*A1);  // (r,Mr)
        float beta  = first ? 0.f : gamma / gamma_old;
        float denom = first ? delta : (delta - beta * gamma / alpha_old);
        float alpha = (gamma < 1e-30f) ? 0.f : gamma / denom;
        float ur = own ? (c_task*(tr - A0) + mfl*c_cls*(tr - A1)) : 0.f;
        float cw = 0.1f*cr + ur;                             // c of w = M r
        cp = cr + beta * cp;
        cq = cw + beta * cq;
        cx += alpha * cp;
        if(it == CG_ITERS - 1 || gamma < 1e-26f) break;      // final sweep skipped
        if(mth) u[tid] = ur;
        __syncthreads();                                     // (b)
        float gv = matvec();                                 // G0 * u_r
        float tw = 0.1f*tr + gv;                             // t of w
        tq = tw + beta * tq;
        cr -= alpha * cq;
        tr -= alpha * tq;
        gamma_old = gamma; alpha_old = alpha; first = false;
    }

    // v = 10*1 + Xs^T c_x  (accumulated into vv[] in LDS)
    __syncthreads();
    if(mth) u[tid] = own ? cx : 0.f;
    __syncthreads();
    const float4* X4 = (const float4*)X;
    const int f4c = tid & 127;
    const int rg  = tid >> 7;
    float4 acc = make_float4(0.f,0.f,0.f,0.f);
    int s = rg;
    for(; s + 28 < nsc; s += 32){
        int n0 = idx_l[s],    n1 = idx_l[s+4],  n2 = idx_l[s+8],  n3 = idx_l[s+12];
        int n4 = idx_l[s+16], n5 = idx_l[s+20], n6 = idx_l[s+24], n7 = idx_l[s+28];
        float w0 = u[s],    w1 = u[s+4],  w2 = u[s+8],  w3 = u[s+12];
        float w4 = u[s+16], w5 = u[s+20], w6 = u[s+24], w7 = u[s+28];
        float4 x0 = X4[(size_t)n0*128 + f4c];
        float4 x1 = X4[(size_t)n1*128 + f4c];
        float4 x2 = X4[(size_t)n2*128 + f4c];
        float4 x3 = X4[(size_t)n3*128 + f4c];
        float4 x4 = X4[(size_t)n4*128 + f4c];
        float4 x5 = X4[(size_t)n5*128 + f4c];
        float4 x6 = X4[(size_t)n6*128 + f4c];
        float4 x7 = X4[(size_t)n7*128 + f4c];
        acc = f4fma(w0,x0, f4fma(w1,x1, f4fma(w2,x2, f4fma(w3,x3, acc))));
        acc = f4fma(w4,x4, f4fma(w5,x5, f4fma(w6,x6, f4fma(w7,x7, acc))));
    }
    for(; s < nsc; s += 4)
        acc = f4fma(u[s], X4[(size_t)idx_l[s]*128 + f4c], acc);
    gl4[rg*128 + f4c] = acc;
    __syncthreads();
    if(tid < 128){
        float4 v = f4add(f4add(gl4[tid], gl4[128+tid]),
                         f4add(gl4[256+tid], gl4[384+tid]));
        v.x += 10.f; v.y += 10.f; v.z += 10.f; v.w += 10.f;
        vv[tid] = v;
    }

    // sm = sum(mean_c), mv = mean_c . v  (one bundle; vv made visible by its
    // internal barrier — each tid<128 reads only its own vv element here)
    const float* mean_c = cls ? pos_mean : neg_mean;
    float psm = 0.f, pmv = 0.f;
    if(tid < 128){
        float4 m4 = ((const float4*)mean_c)[b*128 + tid];
        float4 v  = vv[tid];
        psm = f4sum(m4);
        pmv = f4dot(m4, v);
    }
    bundle(psm, pmv, 0.f, 0.f, 0.f, S);
    const float sm = S[0], mv = S[1];
    const float scale = expf(log_scale[0]);

    // query loop: 8 waves, 2 rows per wave per iteration
    const float4 va = vv[lane], vb = vv[lane + 64];
    for(int r = wave; r < nqc; r += 16){
        int r2 = r + 8;
        bool has2 = r2 < nqc;
        int n  = qidx_l[r];
        int n2 = qidx_l[has2 ? r2 : r];
        const float4* xr = (const float4*)(X + (size_t)n  * DDIM);
        const float4* yr = (const float4*)(X + (size_t)n2 * DDIM);
        float4 x0 = xr[lane], x1 = xr[lane + 64];
        float4 y0 = yr[lane], y1 = yr[lane + 64];
        float t1 = f4dot(x0, va) + f4dot(x1, vb);
        float s1 = f4sum(x0) + f4sum(x1);
        float t2 = f4dot(y0, va) + f4dot(y1, vb);
        float s2 = f4sum(y0) + f4sum(y1);
        #pragma unroll
        for(int off = 32; off; off >>= 1){
            t1 += __shfl_xor(t1, off);
            s1 += __shfl_xor(s1, off);
            t2 += __shfl_xor(t2, off);
            s2 += __shfl_xor(s2, off);
        }
        if(lane == 0){
            out[(size_t)(b*LPAD + r)*2 + cls] = (t1 - mv) * (s1 - sm) * scale;
            if(has2)
                out[(size_t)(b*LPAD + r2)*2 + cls] = (t2 - mv) * (s2 - sm) * scale;
        }
    }
    for(int r = nqc + tid; r < LPAD; r += 512)
        out[(size_t)(b*LPAD + r)*2 + cls] = 0.f;
}

// ---------------------------------------------------------------------------
extern "C" void kernel_launch(void* const* d_in, const int* in_sizes, int n_in,
                              void* d_out, int out_size, void* d_ws, size_t ws_size,
                              hipStream_t stream)
{
    const float* X         = (const float*)d_in[0];
    const float* log_scale = (const float*)d_in[1];
    const int*   labels    = (const int*)d_in[2];
    const int*   is_query  = (const int*)d_in[3];
    const int*   bidx      = (const int*)d_in[4];
    const int N = in_sizes[2];

    char* ws = (char*)d_ws;
    auto alloc = [&](size_t bytes) -> char* {
        char* p = ws;
        ws += (bytes + 255) & ~(size_t)255;
        return p;
    };
    int*   sup_idx   = (int*)  alloc((size_t)EPISODES * LPAD * sizeof(int));
    int*   qry_idx   = (int*)  alloc((size_t)EPISODES * LPAD * sizeof(int));
    int*   sup_lab   = (int*)  alloc((size_t)EPISODES * LPAD * sizeof(int));
    int*   counts    = (int*)  alloc((size_t)EPISODES * 4 * sizeof(int));
    float* task_mean = (float*)alloc((size_t)EPISODES * DDIM * sizeof(float));
    float* pos_mean  = (float*)alloc((size_t)EPISODES * DDIM * sizeof(float));
    float* neg_mean  = (float*)alloc((size_t)EPISODES * DDIM * sizeof(float));
    float* row_sums2 = (float*)alloc((size_t)EPISODES * LPAD * 2 * sizeof(float));
    float* G0        = (float*)alloc((size_t)EPISODES * NS_CAP * NS_CAP * sizeof(float));
    unsigned short* Xbf = (unsigned short*)alloc(
                          (size_t)EPISODES * NS_CAP * XBF_ROW * sizeof(unsigned short));
    (void)ws_size;
    (void)task_mean;

    k_prep<<<EPISODES*2, 256, 0, stream>>>(labels, is_query, bidx, X, N,
                                           sup_idx, qry_idx, sup_lab, counts,
                                           task_mean, pos_mean, neg_mean, row_sums2,
                                           Xbf);
    k_gram<<<EPISODES * NPAIRS, 256, 0, stream>>>(Xbf, counts, G0);
    k_cgc<<<EPISODES * 2, 512, GL_F4 * sizeof(float4), stream>>>(
                                            X, G0, sup_idx, sup_lab, counts,
                                            row_sums2, qry_idx, pos_mean, neg_mean,
                                            log_scale, (float*)d_out);
}